// Round 4
// baseline (2367.397 us; speedup 1.0000x reference)
//
#include <hip/hip_runtime.h>
#include <math.h>

// ---------------------------------------------------------------------------
// QFullResnetBlock: two quantum passes (13x 12-qubit sims + 1x 4-qubit sim per
// batch elem) + groupnorm/time-FiLM/swish glue + residual.
//
// 12-qubit sim: TWO waves per sim, 32 amps per thread; 2 sims per 256-thread
// workgroup. Amplitude index amp (12 bits) = (wv << 11) | (lane << 5) | k :
//   bits 0..4  = k    (register-local, sr[32]/si[32] = 64 VGPR state)
//   bits 5..10 = lane (lane bit L = amp bit 5+L; exchange via __shfl_xor)
//   bit  11    = wv   (wave within sim; exchange via LDS, 1 CRX per layer)
// Qubit w lives at amp bit (11-w).
//
// Why 32 amps (R1-R3 post-mortems): 64-amp state = 128 VGPR is wedged between
// spill (allocator target <160 -> hundreds of MB scratch, R1/R3) and occupancy
// (target >168 -> <=3 waves/SIMD, R2 latency-bound at VALUBusy 46%). 32-amp
// state + temps fits a 128-VGPR budget -> 4 waves/SIMD with zero scratch.
// __launch_bounds__(256, 4) pins that budget.
//
// Gate pattern per layer l, group j, m=0..3 (amp-bit positions):
//   crz/crx target bit pt = 4j+m, control bit pc = (4j+8+m)%12
//   j=0: pt=m (k, local pairs); pc=8+m -> lane bits 3,4,5 (m<3), wv (m=3)
//   j=1: pt=4+m -> k bit 4 (m=0), lane bits 0..2 (m>=1); pc=m (k, free skip)
//   j=2: pt=8+m -> lane bits 3,4,5 (m<3), wv (m=3 -> LDS); pc=4+m -> k bit 4
//        (m=0), lane bits 0..2 (m>=1, thread-uniform)
// ---------------------------------------------------------------------------

#define PI_F 3.14159265358979323846f

// CRZ, control = k bit PC, target = k bit PT
template<int PC, int PT>
__device__ __forceinline__ void crz_kk(float cg, float sg, float* sr, float* si)
{
#pragma unroll
    for (int k = 0; k < 32; ++k) {
        if (!((k >> PC) & 1)) continue;
        float ss = ((k >> PT) & 1) ? sg : -sg;
        float r = sr[k], im = si[k];
        sr[k] = cg * r  - ss * im;
        si[k] = cg * im + ss * r;
    }
}

// CRZ, control = k bit PC, target = lane bit LT (sign hoisted per thread)
template<int PC, int LT>
__device__ __forceinline__ void crz_kl(float cg, float sg, float* sr, float* si,
                                       int lane)
{
    float ss = ((lane >> LT) & 1) ? sg : -sg;
#pragma unroll
    for (int k = 0; k < 32; ++k) {
        if (!((k >> PC) & 1)) continue;
        float r = sr[k], im = si[k];
        sr[k] = cg * r  - ss * im;
        si[k] = cg * im + ss * r;
    }
}

// CRX, control folded into (cg,sg) [identity when inactive], target = k bit PT
template<int PT>
__device__ __forceinline__ void crx_loc(float cg, float sg, float* sr, float* si)
{
#pragma unroll
    for (int k = 0; k < 32; ++k) {
        if ((k >> PT) & 1) continue;
        int p = k | (1 << PT);
        float r0 = sr[k], i0 = si[k], r1 = sr[p], i1 = si[p];
        sr[k] = cg * r0 + sg * i1;  si[k] = cg * i0 - sg * r1;
        sr[p] = cg * r1 + sg * i0;  si[p] = cg * i1 - sg * r0;
    }
}

// CRX, control = k bit PC, target = k bit PT
template<int PC, int PT>
__device__ __forceinline__ void crx_kk(float cg, float sg, float* sr, float* si)
{
#pragma unroll
    for (int k = 0; k < 32; ++k) {
        if (!((k >> PC) & 1) || ((k >> PT) & 1)) continue;
        int p = k | (1 << PT);
        float r0 = sr[k], i0 = si[k], r1 = sr[p], i1 = si[p];
        sr[k] = cg * r0 + sg * i1;  si[k] = cg * i0 - sg * r1;
        sr[p] = cg * r1 + sg * i0;  si[p] = cg * i1 - sg * r0;
    }
}

// CRX, control = k bit PC (compile-time skip), target = lane bit LT (shuffle)
template<int PC, int LT>
__device__ __forceinline__ void crx_sh_k(float cg, float sg, float* sr, float* si)
{
#pragma unroll
    for (int k = 0; k < 32; ++k) {
        if (!((k >> PC) & 1)) continue;
        float br = __shfl_xor(sr[k], 1 << LT, 64);
        float bi = __shfl_xor(si[k], 1 << LT, 64);
        float r = sr[k], im = si[k];
        sr[k] = cg * r  + sg * bi;
        si[k] = cg * im - sg * br;
    }
}

// CRX, control folded (thread-uniform), target = lane bit LT (shuffle, all k)
template<int LT>
__device__ __forceinline__ void crx_sh_all(float cg, float sg, float* sr, float* si)
{
#pragma unroll
    for (int k = 0; k < 32; ++k) {
        float br = __shfl_xor(sr[k], 1 << LT, 64);
        float bi = __shfl_xor(si[k], 1 << LT, 64);
        float r = sr[k], im = si[k];
        sr[k] = cg * r  + sg * bi;
        si[k] = cg * im - sg * br;
    }
}

// Fused j=0 CRZ group: gates m=0..3; ctrl = lane bits 3,4,5 (m<3) / wv (m=3),
// all thread-uniform; target = k bit m. Multiplier depends only on k&15;
// M[15-t] = conj(M[t]) -> 8-entry complex table.
__device__ __forceinline__ void crz_j0_fused(const float* a, float* sr, float* si,
                                             int lane, int wv)
{
    float gr[4], gi[4];
#pragma unroll
    for (int m = 0; m < 4; ++m) {
        bool cb = (m < 3) ? ((lane >> (3 + m)) & 1) : (wv != 0);
        gr[m] = cb ? a[2 * m]     : 1.0f;
        gi[m] = cb ? a[2 * m + 1] : 0.0f;
    }
    // pair products with conjugate symmetry: store [t1t0]=00 and 01
    float u0 = gr[1] * gr[0], v0 = gi[1] * gi[0];
    float w0 = gr[1] * gi[0], z0 = gi[1] * gr[0];
    float p01r[2] = { u0 - v0, u0 + v0 };
    float p01i[2] = { -(w0 + z0), w0 - z0 };
    float u1 = gr[3] * gr[2], v1 = gi[3] * gi[2];
    float w1 = gr[3] * gi[2], z1 = gi[3] * gr[2];
    float p23r[2] = { u1 - v1, u1 + v1 };
    float p23i[2] = { -(w1 + z1), w1 - z1 };

    float Mr[8], Mi[8];
#pragma unroll
    for (int t = 0; t < 8; ++t) {
        const int t10 = t & 3, t2 = (t >> 2) & 1;
        float br = (t10 == 0 || t10 == 3) ? p01r[0] : p01r[1];
        float bi = (t10 == 0) ? p01i[0] : (t10 == 1) ? p01i[1]
                 : (t10 == 2) ? -p01i[1] : -p01i[0];
        float ar = p23r[t2], ai = p23i[t2];
        Mr[t] = ar * br - ai * bi;
        Mi[t] = ar * bi + ai * br;
    }
#pragma unroll
    for (int k = 0; k < 32; ++k) {
        const int t = k & 15;
        float mr = (t < 8) ? Mr[t] : Mr[15 - t];
        float mi = (t < 8) ? Mi[t] : -Mi[15 - t];
        float r = sr[k], im = si[k];
        sr[k] = mr * r  - mi * im;
        si[k] = mr * im + mi * r;
    }
}

// Fused j=2 CRZ group (coeffs a[0..7] = layer base + 32):
//  m=0: ctrl k bit 4,   sign lane bit 3
//  m=1: ctrl lane bit 0, sign lane bit 4   (thread-uniform)
//  m=2: ctrl lane bit 1, sign lane bit 5   (thread-uniform)
//  m=3: ctrl lane bit 2, sign wv           (thread-uniform)
// Multiplier depends only on k bit 4 -> 2-entry table.
__device__ __forceinline__ void crz_j2_fused(const float* a, float* sr, float* si,
                                             int lane, int wv)
{
    float s0p = ((lane >> 3) & 1) ? a[1] : -a[1];
    bool cb1 = lane & 1;
    float sg1 = ((lane >> 4) & 1) ? a[3] : -a[3];
    float g1r = cb1 ? a[2] : 1.0f, g1i = cb1 ? sg1 : 0.0f;
    bool cb2 = (lane >> 1) & 1;
    float sg2 = ((lane >> 5) & 1) ? a[5] : -a[5];
    float g2r = cb2 ? a[4] : 1.0f, g2i = cb2 ? sg2 : 0.0f;
    bool cb3 = (lane >> 2) & 1;
    float sg3 = wv ? a[7] : -a[7];
    float g3r = cb3 ? a[6] : 1.0f, g3i = cb3 ? sg3 : 0.0f;
    float t12r = g1r * g2r - g1i * g2i, t12i = g1r * g2i + g1i * g2r;
    float Sr  = t12r * g3r - t12i * g3i;
    float Si_ = t12r * g3i + t12i * g3r;
    float T1r = Sr * a[0] - Si_ * s0p;
    float T1i = Sr * s0p + Si_ * a[0];
#pragma unroll
    for (int k = 0; k < 32; ++k) {
        float tr = (k >> 4) ? T1r : Sr;
        float ti = (k >> 4) ? T1i : Si_;
        float r = sr[k], im = si[k];
        sr[k] = tr * r  - ti * im;
        si[k] = tr * im + ti * r;
    }
}

__global__ void __launch_bounds__(256, 4)
qpass12_kernel(const float* __restrict__ inp, const float* __restrict__ cs,
               float* __restrict__ outp)
{
    // exchange buffer: [sim][wv][ai 0..31][66] floats, stride 66 -> 2-way banks
    __shared__ float xbuf[2 * 2 * 32 * 66];   // 33792 B
    const int tid  = threadIdx.x;
    const int simL = tid >> 7;            // sim within WG (0,1)
    const int ts   = tid & 127;           // thread within sim
    const int wv   = ts >> 6;             // amp bit 11
    const int lane = ts & 63;             // amp bits 5..10
    const int sim  = blockIdx.x * 2 + simL;
    const int ci = sim % 13;
    const int b  = sim / 13;
    const float* csc = cs + ci * 144;     // 72 gates * (cos,sin)
    const int ibase = b * 160 + ci * 3;   // (B,2,2,40) flat; sp stride 40

    // data angles: qubit w <- inp[b, w/3, (w%3)+3*ci]
    float cw[12], sw[12];
#pragma unroll
    for (int w = 0; w < 12; ++w) {
        float x = inp[ibase + (w / 3) * 40 + (w % 3)];
        __sincosf(0.5f * x, &sw[w], &cw[w]);
    }

    // product-state init: qubit w at amp bit 11-w.
    // thread-uniform prefactor: qubit 0 <- wv; qubits 1..6 <- lane bit 6-w
    float pref = wv ? sw[0] : cw[0];
#pragma unroll
    for (int w = 1; w < 7; ++w)
        pref *= ((lane >> (6 - w)) & 1) ? sw[w] : cw[w];

    // k tables: fb over k bits 0..2 (qubits 11,10,9), eb over bits 3..4 (8,7)
    float fb[8], eb[4];
#pragma unroll
    for (int t = 0; t < 8; ++t)
        fb[t] = ((t & 1) ? sw[11] : cw[11]) * ((t & 2) ? sw[10] : cw[10]) *
                ((t & 4) ? sw[9] : cw[9]);
#pragma unroll
    for (int t = 0; t < 4; ++t)
        eb[t] = pref * ((t & 1) ? sw[8] : cw[8]) * ((t & 2) ? sw[7] : cw[7]);

    // phase (-i)^popc(amp)
    const int pl = (__popc(lane) + wv) & 3;
    float oa = (pl == 0) ? 1.0f : (pl == 2) ? -1.0f : 0.0f;
    float ob = (pl == 1) ? -1.0f : (pl == 3) ? 1.0f : 0.0f;

    float sr[32], si[32];
#pragma unroll
    for (int k = 0; k < 32; ++k) {
        float v = eb[k >> 3] * fb[k & 7];
        const int q = __popc(k) & 3;
        if (q == 0)      { sr[k] =  v * oa; si[k] =  v * ob; }
        else if (q == 1) { sr[k] =  v * ob; si[k] = -v * oa; }
        else if (q == 2) { sr[k] = -v * oa; si[k] = -v * ob; }
        else             { sr[k] = -v * ob; si[k] =  v * oa; }
    }

    // cross-wave exchange addressing (j=2 m=3 CRX: ctrl = lane bit 2)
    const bool act = (lane >> 2) & 1;
    const int  ai  = ((lane >> 3) << 2) | (lane & 3);   // compress free bits
    float* xw = &xbuf[(((simL << 1) | wv) * 32 + ai) * 66];
    float* xr = &xbuf[(((simL << 1) | (wv ^ 1)) * 32 + ai) * 66];

#pragma unroll 1
    for (int l = 0; l < 3; ++l) {
        const float* a = csc + l * 48;

        // ---- group j=0: tgt k bits 0..3; ctrl lane 3,4,5 / wv (uniform) ----
        crz_j0_fused(a, sr, si, lane, wv);
        { bool cb = (lane >> 3) & 1;
          crx_loc<0>(cb ? a[ 8] : 1.0f, cb ? a[ 9] : 0.0f, sr, si); }
        { bool cb = (lane >> 4) & 1;
          crx_loc<1>(cb ? a[10] : 1.0f, cb ? a[11] : 0.0f, sr, si); }
        { bool cb = (lane >> 5) & 1;
          crx_loc<2>(cb ? a[12] : 1.0f, cb ? a[13] : 0.0f, sr, si); }
        { bool cb = wv != 0;
          crx_loc<3>(cb ? a[14] : 1.0f, cb ? a[15] : 0.0f, sr, si); }

        // ---- group j=1: tgt k bit 4 / lane 0..2; ctrl k bits 0..3 ----
        crz_kk<0, 4>(a[16], a[17], sr, si);
        crz_kl<1, 0>(a[18], a[19], sr, si, lane);
        crz_kl<2, 1>(a[20], a[21], sr, si, lane);
        crz_kl<3, 2>(a[22], a[23], sr, si, lane);
        crx_kk<0, 4>(a[24], a[25], sr, si);
        crx_sh_k<1, 0>(a[26], a[27], sr, si);
        crx_sh_k<2, 1>(a[28], a[29], sr, si);
        crx_sh_k<3, 2>(a[30], a[31], sr, si);

        // ---- group j=2: tgt lane 3,4,5 / wv; ctrl k bit 4 / lane 0..2 ----
        crz_j2_fused(a + 32, sr, si, lane, wv);
        crx_sh_k<4, 3>(a[40], a[41], sr, si);
        { bool cb = lane & 1;
          crx_sh_all<4>(cb ? a[42] : 1.0f, cb ? a[43] : 0.0f, sr, si); }
        { bool cb = (lane >> 1) & 1;
          crx_sh_all<5>(cb ? a[44] : 1.0f, cb ? a[45] : 0.0f, sr, si); }
        // m=3: cross-wave CRX (tgt wv), ctrl lane bit 2 (same for partner)
        __syncthreads();
        if (act) {
#pragma unroll
            for (int k = 0; k < 32; ++k) {
                xw[2 * k]     = sr[k];
                xw[2 * k + 1] = si[k];
            }
        }
        __syncthreads();
        if (act) {
            float cg = a[46], sg = a[47];
#pragma unroll
            for (int k = 0; k < 32; ++k) {
                float br = xr[2 * k], bi = xr[2 * k + 1];
                float r = sr[k], im = si[k];
                sr[k] = cg * r  + sg * bi;
                si[k] = cg * im - sg * br;
            }
        }
    }

    // expectation values <Z_w>; reuse sr[] as probability array
    float total = 0.0f;
#pragma unroll
    for (int k = 0; k < 32; ++k) {
        sr[k] = sr[k] * sr[k] + si[k] * si[k];
        total += sr[k];
    }
    float v12[12];
    v12[0] = wv ? -total : total;
#pragma unroll
    for (int w = 1; w < 7; ++w)
        v12[w] = ((lane >> (6 - w)) & 1) ? -total : total;
#pragma unroll
    for (int w = 7; w < 12; ++w) {
        float acc = 0.0f;
#pragma unroll
        for (int k = 0; k < 32; ++k)
            acc += ((k >> (11 - w)) & 1) ? -sr[k] : sr[k];
        v12[w] = acc;
    }
    // in-wave butterfly reduce (64 lanes)
#pragma unroll
    for (int w = 0; w < 12; ++w) {
#pragma unroll
        for (int off = 1; off < 64; off <<= 1)
            v12[w] += __shfl_xor(v12[w], off, 64);
    }
    // cross-wave combine via LDS (reuse xbuf; barrier protects last exchange)
    __syncthreads();
    if (lane == 0) {
#pragma unroll
        for (int w = 0; w < 12; ++w)
            xbuf[((simL << 1) | wv) * 12 + w] = v12[w];
    }
    __syncthreads();
    if (ts < 12) {
        float z = xbuf[(simL << 1) * 12 + ts] +
                  xbuf[((simL << 1) | 1) * 12 + ts];
        outp[ibase + (ts / 3) * 40 + (ts % 3)] = z;
    }
}

__global__ void q4_kernel(const float* __restrict__ inp,
                          const float* __restrict__ cs4,
                          float* __restrict__ outp)
{
    int b = blockIdx.x * blockDim.x + threadIdx.x;
    if (b >= 1024) return;
    float cw[4], sw[4];
#pragma unroll
    for (int j = 0; j < 4; ++j) {
        float x = inp[(b * 4 + j) * 40 + 39];
        __sincosf(0.5f * x, &sw[j], &cw[j]);
    }
    float sr[16], si[16];
#pragma unroll
    for (int k = 0; k < 16; ++k) {
        float v = 1.0f;
#pragma unroll
        for (int j = 0; j < 4; ++j)
            v *= ((k >> (3 - j)) & 1) ? sw[j] : cw[j];
        int ph = __popc(k) & 3;
        sr[k] = (ph == 0) ? v : (ph == 2) ? -v : 0.0f;
        si[k] = (ph == 1) ? -v : (ph == 3) ? v : 0.0f;
    }
#pragma unroll
    for (int l = 0; l < 4; ++l) {
        // RX(theta[4l+w]) on qubit w (bit 3-w)
#pragma unroll
        for (int w = 0; w < 4; ++w) {
            float cg = cs4[2 * (4 * l + w)], sg = cs4[2 * (4 * l + w) + 1];
            const int m = 1 << (3 - w);
#pragma unroll
            for (int k = 0; k < 16; ++k) {
                if (k & m) continue;
                int p2 = k | m;
                float r0 = sr[k], i0 = si[k], r1 = sr[p2], i1 = si[p2];
                sr[k]  = cg * r0 + sg * i1;  si[k]  = cg * i0 - sg * r1;
                sr[p2] = cg * r1 + sg * i0;  si[p2] = cg * i1 - sg * r0;
            }
        }
        // CNOT (0,1),(1,2),(2,3),(3,0)
#pragma unroll
        for (int e = 0; e < 4; ++e) {
            const int cq = e, tq = (e + 1) & 3;
            const int pcb = 1 << (3 - cq), ptb = 1 << (3 - tq);
#pragma unroll
            for (int k = 0; k < 16; ++k) {
                if (!(k & pcb)) continue;
                if (k & ptb) continue;
                int p2 = k | ptb;
                float tr = sr[k], ti = si[k];
                sr[k] = sr[p2]; si[k] = si[p2];
                sr[p2] = tr;    si[p2] = ti;
            }
        }
    }
    float p[16];
#pragma unroll
    for (int k = 0; k < 16; ++k) p[k] = sr[k] * sr[k] + si[k] * si[k];
#pragma unroll
    for (int j = 0; j < 4; ++j) {
        float z = 0.0f;
#pragma unroll
        for (int k = 0; k < 16; ++k)
            z += ((k >> (3 - j)) & 1) ? -p[k] : p[k];
        outp[(b * 4 + j) * 40 + 39] = z;
    }
}

__global__ void prep_kernel(const float* __restrict__ q12,
                            const float* __restrict__ q4,
                            float* __restrict__ cs12,
                            float* __restrict__ cs4)
{
    int idx = blockIdx.x * 256 + threadIdx.x;
    if (idx < 26 * 72) {
        // gate angle = 2*pi*p, half-angle = pi*p
        float s, c;
        sincosf(PI_F * q12[idx], &s, &c);
        cs12[2 * idx]     = c;
        cs12[2 * idx + 1] = s;
    }
    if (idx < 16) {
        float s, c;
        sincosf(0.5f * q4[idx], &s, &c);
        cs4[2 * idx]     = c;
        cs4[2 * idx + 1] = s;
    }
}

__global__ void tmlp_kernel(const float* __restrict__ emb,
                            const float* __restrict__ W,
                            const float* __restrict__ bias,
                            float* __restrict__ t)
{
    __shared__ float se[128];
    int b = blockIdx.x, tid = threadIdx.x;
    float e = emb[b * 128 + tid];
    se[tid] = e / (1.0f + __expf(-e));
    __syncthreads();
    if (tid < 80) {
        float acc = bias[tid];
        for (int k = 0; k < 128; ++k) acc += se[k] * W[k * 80 + tid];
        t[b * 80 + tid] = acc;
    }
}

__global__ void gn0_kernel(const float* __restrict__ h, const float* __restrict__ t,
                           const float* __restrict__ sc, const float* __restrict__ bi,
                           float* __restrict__ outp)
{
    __shared__ float v[160];
    __shared__ float mu[10], rstd[10];
    int b = blockIdx.x, tid = threadIdx.x;
    if (tid < 160) v[tid] = h[b * 160 + tid];
    __syncthreads();
    if (tid < 10) {
        float s1 = 0.0f, s2 = 0.0f;
#pragma unroll
        for (int sp = 0; sp < 4; ++sp)
#pragma unroll
            for (int k = 0; k < 4; ++k) {
                float x = v[sp * 40 + tid * 4 + k];
                s1 += x; s2 += x * x;
            }
        float m = s1 * (1.0f / 16.0f);
        float var = s2 * (1.0f / 16.0f) - m * m;
        mu[tid] = m; rstd[tid] = rsqrtf(var + 1e-6f);
    }
    __syncthreads();
    if (tid < 160) {
        int ch = tid % 40;
        int g = ch >> 2;
        float hn = (v[tid] - mu[g]) * rstd[g] * sc[ch] + bi[ch];
        float scale = t[b * 80 + ch], shift = t[b * 80 + 40 + ch];
        float z = hn * (1.0f + scale) + shift;
        outp[b * 160 + tid] = z / (1.0f + __expf(-z));
    }
}

__global__ void gn1_kernel(const float* __restrict__ h, const float* __restrict__ x,
                           const float* __restrict__ sc, const float* __restrict__ bi,
                           float* __restrict__ outp)
{
    __shared__ float v[160];
    __shared__ float mu[10], rstd[10];
    int b = blockIdx.x, tid = threadIdx.x;
    if (tid < 160) v[tid] = h[b * 160 + tid];
    __syncthreads();
    if (tid < 10) {
        float s1 = 0.0f, s2 = 0.0f;
#pragma unroll
        for (int sp = 0; sp < 4; ++sp)
#pragma unroll
            for (int k = 0; k < 4; ++k) {
                float xx = v[sp * 40 + tid * 4 + k];
                s1 += xx; s2 += xx * xx;
            }
        float m = s1 * (1.0f / 16.0f);
        float var = s2 * (1.0f / 16.0f) - m * m;
        mu[tid] = m; rstd[tid] = rsqrtf(var + 1e-6f);
    }
    __syncthreads();
    if (tid < 160) {
        int ch = tid % 40;
        int g = ch >> 2;
        float hn = (v[tid] - mu[g]) * rstd[g] * sc[ch] + bi[ch];
        float sws = hn / (1.0f + __expf(-hn));
        outp[b * 160 + tid] = x[b * 160 + tid] + sws;
    }
}

extern "C" void kernel_launch(void* const* d_in, const int* in_sizes, int n_in,
                              void* d_out, int out_size, void* d_ws, size_t ws_size,
                              hipStream_t stream)
{
    const float* x    = (const float*)d_in[0];
    const float* temb = (const float*)d_in[1];
    const float* q12  = (const float*)d_in[2];
    const float* q4   = (const float*)d_in[3];
    const float* gn0s = (const float*)d_in[4];
    const float* gn0b = (const float*)d_in[5];
    const float* gn1s = (const float*)d_in[6];
    const float* gn1b = (const float*)d_in[7];
    const float* tw   = (const float*)d_in[8];
    const float* tb   = (const float*)d_in[9];
    float* out = (float*)d_out;

    float* ws   = (float*)d_ws;
    float* cs12 = ws;               // 26*72*2   = 3744
    float* cs4  = cs12 + 3744;      // 32
    float* tbuf = cs4 + 32;         // 1024*80   = 81920
    float* A    = tbuf + 81920;     // 1024*160  = 163840 (raw qpass out)
    float* Bf   = A + 163840;       // 1024*160  = 163840 (gn0 out / qpass2 in)

    prep_kernel<<<8, 256, 0, stream>>>(q12, q4, cs12, cs4);
    tmlp_kernel<<<1024, 128, 0, stream>>>(temb, tw, tb, tbuf);

    // pass 1  (6656 blocks x 2 sims x 2 waves = 13312 sims)
    qpass12_kernel<<<6656, 256, 0, stream>>>(x, cs12, A);
    q4_kernel<<<16, 64, 0, stream>>>(x, cs4, A);
    gn0_kernel<<<1024, 160, 0, stream>>>(A, tbuf, gn0s, gn0b, Bf);

    // pass 2
    qpass12_kernel<<<6656, 256, 0, stream>>>(Bf, cs12 + 13 * 144, A);
    q4_kernel<<<16, 64, 0, stream>>>(Bf, cs4, A);
    gn1_kernel<<<1024, 160, 0, stream>>>(A, x, gn1s, gn1b, out);
}

// Round 5
// 900.042 us; speedup vs baseline: 2.6303x; 2.6303x over previous
//
#include <hip/hip_runtime.h>
#include <math.h>

// ---------------------------------------------------------------------------
// QFullResnetBlock: two quantum passes (13x 12-qubit sims + 1x 4-qubit sim per
// batch elem) + groupnorm/time-FiLM/swish glue + residual.
//
// 12-qubit sim: TWO waves per sim, 32 amps per thread; 2 sims per 256-thread
// workgroup. Amplitude index amp (12 bits) = (wv << 11) | (lane << 5) | k :
//   bits 0..4  = k    (register-local, sr[32]/si[32] = 64 VGPR state)
//   bits 5..10 = lane (lane bit L = amp bit 5+L; exchange via __shfl_xor)
//   bit  11    = wv   (wave within sim; exchange via LDS, 1 CRX per layer)
// Qubit w lives at amp bit (11-w).
//
// REGISTER ALLOCATION (R1-R4 post-mortems): the GCN scheduler, given only a
// min-waves bound (__launch_bounds__ 2nd arg), chases ~2x that occupancy and
// spills every temp to scratch (R1: 465 MB, R4: 3.9 GB write-back). The only
// incantation observed to produce a ZERO-SPILL allocation with multi-wave WGs
// is __launch_bounds__(256) + amdgpu_waves_per_eu(2,3), which landed at the
// 128-VGPR bucket in R3. The 32-amp body needs ~90-110 live regs -> fits 128.
//
// Gate pattern per layer l, group j, m=0..3 (amp-bit positions):
//   crz/crx target bit pt = 4j+m, control bit pc = (4j+8+m)%12
//   j=0: pt=m (k, local pairs); pc=8+m -> lane bits 3,4,5 (m<3), wv (m=3)
//   j=1: pt=4+m -> k bit 4 (m=0), lane bits 0..2 (m>=1); pc=m (k, free skip)
//   j=2: pt=8+m -> lane bits 3,4,5 (m<3), wv (m=3 -> LDS); pc=4+m -> k bit 4
//        (m=0), lane bits 0..2 (m>=1, thread-uniform)
// ---------------------------------------------------------------------------

#define PI_F 3.14159265358979323846f

// CRZ, control = k bit PC, target = k bit PT
template<int PC, int PT>
__device__ __forceinline__ void crz_kk(float cg, float sg, float* sr, float* si)
{
#pragma unroll
    for (int k = 0; k < 32; ++k) {
        if (!((k >> PC) & 1)) continue;
        float ss = ((k >> PT) & 1) ? sg : -sg;
        float r = sr[k], im = si[k];
        sr[k] = cg * r  - ss * im;
        si[k] = cg * im + ss * r;
    }
}

// CRZ, control = k bit PC, target = lane bit LT (sign hoisted per thread)
template<int PC, int LT>
__device__ __forceinline__ void crz_kl(float cg, float sg, float* sr, float* si,
                                       int lane)
{
    float ss = ((lane >> LT) & 1) ? sg : -sg;
#pragma unroll
    for (int k = 0; k < 32; ++k) {
        if (!((k >> PC) & 1)) continue;
        float r = sr[k], im = si[k];
        sr[k] = cg * r  - ss * im;
        si[k] = cg * im + ss * r;
    }
}

// CRX, control folded into (cg,sg) [identity when inactive], target = k bit PT
template<int PT>
__device__ __forceinline__ void crx_loc(float cg, float sg, float* sr, float* si)
{
#pragma unroll
    for (int k = 0; k < 32; ++k) {
        if ((k >> PT) & 1) continue;
        int p = k | (1 << PT);
        float r0 = sr[k], i0 = si[k], r1 = sr[p], i1 = si[p];
        sr[k] = cg * r0 + sg * i1;  si[k] = cg * i0 - sg * r1;
        sr[p] = cg * r1 + sg * i0;  si[p] = cg * i1 - sg * r0;
    }
}

// CRX, control = k bit PC, target = k bit PT
template<int PC, int PT>
__device__ __forceinline__ void crx_kk(float cg, float sg, float* sr, float* si)
{
#pragma unroll
    for (int k = 0; k < 32; ++k) {
        if (!((k >> PC) & 1) || ((k >> PT) & 1)) continue;
        int p = k | (1 << PT);
        float r0 = sr[k], i0 = si[k], r1 = sr[p], i1 = si[p];
        sr[k] = cg * r0 + sg * i1;  si[k] = cg * i0 - sg * r1;
        sr[p] = cg * r1 + sg * i0;  si[p] = cg * i1 - sg * r0;
    }
}

// CRX, control = k bit PC (compile-time skip), target = lane bit LT (shuffle)
template<int PC, int LT>
__device__ __forceinline__ void crx_sh_k(float cg, float sg, float* sr, float* si)
{
#pragma unroll
    for (int k = 0; k < 32; ++k) {
        if (!((k >> PC) & 1)) continue;
        float br = __shfl_xor(sr[k], 1 << LT, 64);
        float bi = __shfl_xor(si[k], 1 << LT, 64);
        float r = sr[k], im = si[k];
        sr[k] = cg * r  + sg * bi;
        si[k] = cg * im - sg * br;
    }
}

// CRX, control folded (thread-uniform), target = lane bit LT (shuffle, all k)
template<int LT>
__device__ __forceinline__ void crx_sh_all(float cg, float sg, float* sr, float* si)
{
#pragma unroll
    for (int k = 0; k < 32; ++k) {
        float br = __shfl_xor(sr[k], 1 << LT, 64);
        float bi = __shfl_xor(si[k], 1 << LT, 64);
        float r = sr[k], im = si[k];
        sr[k] = cg * r  + sg * bi;
        si[k] = cg * im - sg * br;
    }
}

// Fused j=0 CRZ group: gates m=0..3; ctrl = lane bits 3,4,5 (m<3) / wv (m=3),
// all thread-uniform; target = k bit m. Multiplier depends only on k&15;
// M[15-t] = conj(M[t]) -> 8-entry complex table.
__device__ __forceinline__ void crz_j0_fused(const float* a, float* sr, float* si,
                                             int lane, int wv)
{
    float gr[4], gi[4];
#pragma unroll
    for (int m = 0; m < 4; ++m) {
        bool cb = (m < 3) ? ((lane >> (3 + m)) & 1) : (wv != 0);
        gr[m] = cb ? a[2 * m]     : 1.0f;
        gi[m] = cb ? a[2 * m + 1] : 0.0f;
    }
    // pair products with conjugate symmetry: store [t1t0]=00 and 01
    float u0 = gr[1] * gr[0], v0 = gi[1] * gi[0];
    float w0 = gr[1] * gi[0], z0 = gi[1] * gr[0];
    float p01r[2] = { u0 - v0, u0 + v0 };
    float p01i[2] = { -(w0 + z0), w0 - z0 };
    float u1 = gr[3] * gr[2], v1 = gi[3] * gi[2];
    float w1 = gr[3] * gi[2], z1 = gi[3] * gr[2];
    float p23r[2] = { u1 - v1, u1 + v1 };
    float p23i[2] = { -(w1 + z1), w1 - z1 };

    float Mr[8], Mi[8];
#pragma unroll
    for (int t = 0; t < 8; ++t) {
        const int t10 = t & 3, t2 = (t >> 2) & 1;
        float br = (t10 == 0 || t10 == 3) ? p01r[0] : p01r[1];
        float bi = (t10 == 0) ? p01i[0] : (t10 == 1) ? p01i[1]
                 : (t10 == 2) ? -p01i[1] : -p01i[0];
        float ar = p23r[t2], ai = p23i[t2];
        Mr[t] = ar * br - ai * bi;
        Mi[t] = ar * bi + ai * br;
    }
#pragma unroll
    for (int k = 0; k < 32; ++k) {
        const int t = k & 15;
        float mr = (t < 8) ? Mr[t] : Mr[15 - t];
        float mi = (t < 8) ? Mi[t] : -Mi[15 - t];
        float r = sr[k], im = si[k];
        sr[k] = mr * r  - mi * im;
        si[k] = mr * im + mi * r;
    }
}

// Fused j=2 CRZ group (coeffs a[0..7] = layer base + 32):
//  m=0: ctrl k bit 4,   sign lane bit 3
//  m=1: ctrl lane bit 0, sign lane bit 4   (thread-uniform)
//  m=2: ctrl lane bit 1, sign lane bit 5   (thread-uniform)
//  m=3: ctrl lane bit 2, sign wv           (thread-uniform)
// Multiplier depends only on k bit 4 -> 2-entry table.
__device__ __forceinline__ void crz_j2_fused(const float* a, float* sr, float* si,
                                             int lane, int wv)
{
    float s0p = ((lane >> 3) & 1) ? a[1] : -a[1];
    bool cb1 = lane & 1;
    float sg1 = ((lane >> 4) & 1) ? a[3] : -a[3];
    float g1r = cb1 ? a[2] : 1.0f, g1i = cb1 ? sg1 : 0.0f;
    bool cb2 = (lane >> 1) & 1;
    float sg2 = ((lane >> 5) & 1) ? a[5] : -a[5];
    float g2r = cb2 ? a[4] : 1.0f, g2i = cb2 ? sg2 : 0.0f;
    bool cb3 = (lane >> 2) & 1;
    float sg3 = wv ? a[7] : -a[7];
    float g3r = cb3 ? a[6] : 1.0f, g3i = cb3 ? sg3 : 0.0f;
    float t12r = g1r * g2r - g1i * g2i, t12i = g1r * g2i + g1i * g2r;
    float Sr  = t12r * g3r - t12i * g3i;
    float Si_ = t12r * g3i + t12i * g3r;
    float T1r = Sr * a[0] - Si_ * s0p;
    float T1i = Sr * s0p + Si_ * a[0];
#pragma unroll
    for (int k = 0; k < 32; ++k) {
        float tr = (k >> 4) ? T1r : Sr;
        float ti = (k >> 4) ? T1i : Si_;
        float r = sr[k], im = si[k];
        sr[k] = tr * r  - ti * im;
        si[k] = tr * im + ti * r;
    }
}

__global__ void __launch_bounds__(256)
__attribute__((amdgpu_waves_per_eu(2, 3)))
qpass12_kernel(const float* __restrict__ inp, const float* __restrict__ cs,
               float* __restrict__ outp)
{
    // exchange buffer: [sim][wv][ai 0..31][66] floats, stride 66 -> 2-way banks
    __shared__ float xbuf[2 * 2 * 32 * 66];   // 33792 B
    const int tid  = threadIdx.x;
    const int simL = tid >> 7;            // sim within WG (0,1)
    const int ts   = tid & 127;           // thread within sim
    const int wv   = ts >> 6;             // amp bit 11
    const int lane = ts & 63;             // amp bits 5..10
    const int sim  = blockIdx.x * 2 + simL;
    const int ci = sim % 13;
    const int b  = sim / 13;
    const float* csc = cs + ci * 144;     // 72 gates * (cos,sin)
    const int ibase = b * 160 + ci * 3;   // (B,2,2,40) flat; sp stride 40

    // data angles: qubit w <- inp[b, w/3, (w%3)+3*ci]
    float cw[12], sw[12];
#pragma unroll
    for (int w = 0; w < 12; ++w) {
        float x = inp[ibase + (w / 3) * 40 + (w % 3)];
        __sincosf(0.5f * x, &sw[w], &cw[w]);
    }

    // product-state init: qubit w at amp bit 11-w.
    // thread-uniform prefactor: qubit 0 <- wv; qubits 1..6 <- lane bit 6-w
    float pref = wv ? sw[0] : cw[0];
#pragma unroll
    for (int w = 1; w < 7; ++w)
        pref *= ((lane >> (6 - w)) & 1) ? sw[w] : cw[w];

    // k tables: fb over k bits 0..2 (qubits 11,10,9), eb over bits 3..4 (8,7)
    float fb[8], eb[4];
#pragma unroll
    for (int t = 0; t < 8; ++t)
        fb[t] = ((t & 1) ? sw[11] : cw[11]) * ((t & 2) ? sw[10] : cw[10]) *
                ((t & 4) ? sw[9] : cw[9]);
#pragma unroll
    for (int t = 0; t < 4; ++t)
        eb[t] = pref * ((t & 1) ? sw[8] : cw[8]) * ((t & 2) ? sw[7] : cw[7]);

    // phase (-i)^popc(amp)
    const int pl = (__popc(lane) + wv) & 3;
    float oa = (pl == 0) ? 1.0f : (pl == 2) ? -1.0f : 0.0f;
    float ob = (pl == 1) ? -1.0f : (pl == 3) ? 1.0f : 0.0f;

    float sr[32], si[32];
#pragma unroll
    for (int k = 0; k < 32; ++k) {
        float v = eb[k >> 3] * fb[k & 7];
        const int q = __popc(k) & 3;
        if (q == 0)      { sr[k] =  v * oa; si[k] =  v * ob; }
        else if (q == 1) { sr[k] =  v * ob; si[k] = -v * oa; }
        else if (q == 2) { sr[k] = -v * oa; si[k] = -v * ob; }
        else             { sr[k] = -v * ob; si[k] =  v * oa; }
    }

    // cross-wave exchange addressing (j=2 m=3 CRX: ctrl = lane bit 2)
    const bool act = (lane >> 2) & 1;
    const int  ai  = ((lane >> 3) << 2) | (lane & 3);   // compress free bits
    float* xw = &xbuf[(((simL << 1) | wv) * 32 + ai) * 66];
    float* xr = &xbuf[(((simL << 1) | (wv ^ 1)) * 32 + ai) * 66];

#pragma unroll 1
    for (int l = 0; l < 3; ++l) {
        const float* a = csc + l * 48;

        // ---- group j=0: tgt k bits 0..3; ctrl lane 3,4,5 / wv (uniform) ----
        crz_j0_fused(a, sr, si, lane, wv);
        { bool cb = (lane >> 3) & 1;
          crx_loc<0>(cb ? a[ 8] : 1.0f, cb ? a[ 9] : 0.0f, sr, si); }
        { bool cb = (lane >> 4) & 1;
          crx_loc<1>(cb ? a[10] : 1.0f, cb ? a[11] : 0.0f, sr, si); }
        { bool cb = (lane >> 5) & 1;
          crx_loc<2>(cb ? a[12] : 1.0f, cb ? a[13] : 0.0f, sr, si); }
        { bool cb = wv != 0;
          crx_loc<3>(cb ? a[14] : 1.0f, cb ? a[15] : 0.0f, sr, si); }

        // ---- group j=1: tgt k bit 4 / lane 0..2; ctrl k bits 0..3 ----
        crz_kk<0, 4>(a[16], a[17], sr, si);
        crz_kl<1, 0>(a[18], a[19], sr, si, lane);
        crz_kl<2, 1>(a[20], a[21], sr, si, lane);
        crz_kl<3, 2>(a[22], a[23], sr, si, lane);
        crx_kk<0, 4>(a[24], a[25], sr, si);
        crx_sh_k<1, 0>(a[26], a[27], sr, si);
        crx_sh_k<2, 1>(a[28], a[29], sr, si);
        crx_sh_k<3, 2>(a[30], a[31], sr, si);

        // ---- group j=2: tgt lane 3,4,5 / wv; ctrl k bit 4 / lane 0..2 ----
        crz_j2_fused(a + 32, sr, si, lane, wv);
        crx_sh_k<4, 3>(a[40], a[41], sr, si);
        { bool cb = lane & 1;
          crx_sh_all<4>(cb ? a[42] : 1.0f, cb ? a[43] : 0.0f, sr, si); }
        { bool cb = (lane >> 1) & 1;
          crx_sh_all<5>(cb ? a[44] : 1.0f, cb ? a[45] : 0.0f, sr, si); }
        // m=3: cross-wave CRX (tgt wv), ctrl lane bit 2 (same for partner)
        __syncthreads();
        if (act) {
#pragma unroll
            for (int k = 0; k < 32; ++k) {
                xw[2 * k]     = sr[k];
                xw[2 * k + 1] = si[k];
            }
        }
        __syncthreads();
        if (act) {
            float cg = a[46], sg = a[47];
#pragma unroll
            for (int k = 0; k < 32; ++k) {
                float br = xr[2 * k], bi = xr[2 * k + 1];
                float r = sr[k], im = si[k];
                sr[k] = cg * r  + sg * bi;
                si[k] = cg * im - sg * br;
            }
        }
    }

    // expectation values <Z_w>; reuse sr[] as probability array
    float total = 0.0f;
#pragma unroll
    for (int k = 0; k < 32; ++k) {
        sr[k] = sr[k] * sr[k] + si[k] * si[k];
        total += sr[k];
    }
    float v12[12];
    v12[0] = wv ? -total : total;
#pragma unroll
    for (int w = 1; w < 7; ++w)
        v12[w] = ((lane >> (6 - w)) & 1) ? -total : total;
#pragma unroll
    for (int w = 7; w < 12; ++w) {
        float acc = 0.0f;
#pragma unroll
        for (int k = 0; k < 32; ++k)
            acc += ((k >> (11 - w)) & 1) ? -sr[k] : sr[k];
        v12[w] = acc;
    }
    // in-wave butterfly reduce (64 lanes)
#pragma unroll
    for (int w = 0; w < 12; ++w) {
#pragma unroll
        for (int off = 1; off < 64; off <<= 1)
            v12[w] += __shfl_xor(v12[w], off, 64);
    }
    // cross-wave combine via LDS (reuse xbuf; barrier protects last exchange)
    __syncthreads();
    if (lane == 0) {
#pragma unroll
        for (int w = 0; w < 12; ++w)
            xbuf[((simL << 1) | wv) * 12 + w] = v12[w];
    }
    __syncthreads();
    if (ts < 12) {
        float z = xbuf[(simL << 1) * 12 + ts] +
                  xbuf[((simL << 1) | 1) * 12 + ts];
        outp[ibase + (ts / 3) * 40 + (ts % 3)] = z;
    }
}

__global__ void q4_kernel(const float* __restrict__ inp,
                          const float* __restrict__ cs4,
                          float* __restrict__ outp)
{
    int b = blockIdx.x * blockDim.x + threadIdx.x;
    if (b >= 1024) return;
    float cw[4], sw[4];
#pragma unroll
    for (int j = 0; j < 4; ++j) {
        float x = inp[(b * 4 + j) * 40 + 39];
        __sincosf(0.5f * x, &sw[j], &cw[j]);
    }
    float sr[16], si[16];
#pragma unroll
    for (int k = 0; k < 16; ++k) {
        float v = 1.0f;
#pragma unroll
        for (int j = 0; j < 4; ++j)
            v *= ((k >> (3 - j)) & 1) ? sw[j] : cw[j];
        int ph = __popc(k) & 3;
        sr[k] = (ph == 0) ? v : (ph == 2) ? -v : 0.0f;
        si[k] = (ph == 1) ? -v : (ph == 3) ? v : 0.0f;
    }
#pragma unroll
    for (int l = 0; l < 4; ++l) {
        // RX(theta[4l+w]) on qubit w (bit 3-w)
#pragma unroll
        for (int w = 0; w < 4; ++w) {
            float cg = cs4[2 * (4 * l + w)], sg = cs4[2 * (4 * l + w) + 1];
            const int m = 1 << (3 - w);
#pragma unroll
            for (int k = 0; k < 16; ++k) {
                if (k & m) continue;
                int p2 = k | m;
                float r0 = sr[k], i0 = si[k], r1 = sr[p2], i1 = si[p2];
                sr[k]  = cg * r0 + sg * i1;  si[k]  = cg * i0 - sg * r1;
                sr[p2] = cg * r1 + sg * i0;  si[p2] = cg * i1 - sg * r0;
            }
        }
        // CNOT (0,1),(1,2),(2,3),(3,0)
#pragma unroll
        for (int e = 0; e < 4; ++e) {
            const int cq = e, tq = (e + 1) & 3;
            const int pcb = 1 << (3 - cq), ptb = 1 << (3 - tq);
#pragma unroll
            for (int k = 0; k < 16; ++k) {
                if (!(k & pcb)) continue;
                if (k & ptb) continue;
                int p2 = k | ptb;
                float tr = sr[k], ti = si[k];
                sr[k] = sr[p2]; si[k] = si[p2];
                sr[p2] = tr;    si[p2] = ti;
            }
        }
    }
    float p[16];
#pragma unroll
    for (int k = 0; k < 16; ++k) p[k] = sr[k] * sr[k] + si[k] * si[k];
#pragma unroll
    for (int j = 0; j < 4; ++j) {
        float z = 0.0f;
#pragma unroll
        for (int k = 0; k < 16; ++k)
            z += ((k >> (3 - j)) & 1) ? -p[k] : p[k];
        outp[(b * 4 + j) * 40 + 39] = z;
    }
}

__global__ void prep_kernel(const float* __restrict__ q12,
                            const float* __restrict__ q4,
                            float* __restrict__ cs12,
                            float* __restrict__ cs4)
{
    int idx = blockIdx.x * 256 + threadIdx.x;
    if (idx < 26 * 72) {
        // gate angle = 2*pi*p, half-angle = pi*p
        float s, c;
        sincosf(PI_F * q12[idx], &s, &c);
        cs12[2 * idx]     = c;
        cs12[2 * idx + 1] = s;
    }
    if (idx < 16) {
        float s, c;
        sincosf(0.5f * q4[idx], &s, &c);
        cs4[2 * idx]     = c;
        cs4[2 * idx + 1] = s;
    }
}

__global__ void tmlp_kernel(const float* __restrict__ emb,
                            const float* __restrict__ W,
                            const float* __restrict__ bias,
                            float* __restrict__ t)
{
    __shared__ float se[128];
    int b = blockIdx.x, tid = threadIdx.x;
    float e = emb[b * 128 + tid];
    se[tid] = e / (1.0f + __expf(-e));
    __syncthreads();
    if (tid < 80) {
        float acc = bias[tid];
        for (int k = 0; k < 128; ++k) acc += se[k] * W[k * 80 + tid];
        t[b * 80 + tid] = acc;
    }
}

__global__ void gn0_kernel(const float* __restrict__ h, const float* __restrict__ t,
                           const float* __restrict__ sc, const float* __restrict__ bi,
                           float* __restrict__ outp)
{
    __shared__ float v[160];
    __shared__ float mu[10], rstd[10];
    int b = blockIdx.x, tid = threadIdx.x;
    if (tid < 160) v[tid] = h[b * 160 + tid];
    __syncthreads();
    if (tid < 10) {
        float s1 = 0.0f, s2 = 0.0f;
#pragma unroll
        for (int sp = 0; sp < 4; ++sp)
#pragma unroll
            for (int k = 0; k < 4; ++k) {
                float x = v[sp * 40 + tid * 4 + k];
                s1 += x; s2 += x * x;
            }
        float m = s1 * (1.0f / 16.0f);
        float var = s2 * (1.0f / 16.0f) - m * m;
        mu[tid] = m; rstd[tid] = rsqrtf(var + 1e-6f);
    }
    __syncthreads();
    if (tid < 160) {
        int ch = tid % 40;
        int g = ch >> 2;
        float hn = (v[tid] - mu[g]) * rstd[g] * sc[ch] + bi[ch];
        float scale = t[b * 80 + ch], shift = t[b * 80 + 40 + ch];
        float z = hn * (1.0f + scale) + shift;
        outp[b * 160 + tid] = z / (1.0f + __expf(-z));
    }
}

__global__ void gn1_kernel(const float* __restrict__ h, const float* __restrict__ x,
                           const float* __restrict__ sc, const float* __restrict__ bi,
                           float* __restrict__ outp)
{
    __shared__ float v[160];
    __shared__ float mu[10], rstd[10];
    int b = blockIdx.x, tid = threadIdx.x;
    if (tid < 160) v[tid] = h[b * 160 + tid];
    __syncthreads();
    if (tid < 10) {
        float s1 = 0.0f, s2 = 0.0f;
#pragma unroll
        for (int sp = 0; sp < 4; ++sp)
#pragma unroll
            for (int k = 0; k < 4; ++k) {
                float xx = v[sp * 40 + tid * 4 + k];
                s1 += xx; s2 += xx * xx;
            }
        float m = s1 * (1.0f / 16.0f);
        float var = s2 * (1.0f / 16.0f) - m * m;
        mu[tid] = m; rstd[tid] = rsqrtf(var + 1e-6f);
    }
    __syncthreads();
    if (tid < 160) {
        int ch = tid % 40;
        int g = ch >> 2;
        float hn = (v[tid] - mu[g]) * rstd[g] * sc[ch] + bi[ch];
        float sws = hn / (1.0f + __expf(-hn));
        outp[b * 160 + tid] = x[b * 160 + tid] + sws;
    }
}

extern "C" void kernel_launch(void* const* d_in, const int* in_sizes, int n_in,
                              void* d_out, int out_size, void* d_ws, size_t ws_size,
                              hipStream_t stream)
{
    const float* x    = (const float*)d_in[0];
    const float* temb = (const float*)d_in[1];
    const float* q12  = (const float*)d_in[2];
    const float* q4   = (const float*)d_in[3];
    const float* gn0s = (const float*)d_in[4];
    const float* gn0b = (const float*)d_in[5];
    const float* gn1s = (const float*)d_in[6];
    const float* gn1b = (const float*)d_in[7];
    const float* tw   = (const float*)d_in[8];
    const float* tb   = (const float*)d_in[9];
    float* out = (float*)d_out;

    float* ws   = (float*)d_ws;
    float* cs12 = ws;               // 26*72*2   = 3744
    float* cs4  = cs12 + 3744;      // 32
    float* tbuf = cs4 + 32;         // 1024*80   = 81920
    float* A    = tbuf + 81920;     // 1024*160  = 163840 (raw qpass out)
    float* Bf   = A + 163840;       // 1024*160  = 163840 (gn0 out / qpass2 in)

    prep_kernel<<<8, 256, 0, stream>>>(q12, q4, cs12, cs4);
    tmlp_kernel<<<1024, 128, 0, stream>>>(temb, tw, tb, tbuf);

    // pass 1  (6656 blocks x 2 sims x 2 waves = 13312 sims)
    qpass12_kernel<<<6656, 256, 0, stream>>>(x, cs12, A);
    q4_kernel<<<16, 64, 0, stream>>>(x, cs4, A);
    gn0_kernel<<<1024, 160, 0, stream>>>(A, tbuf, gn0s, gn0b, Bf);

    // pass 2
    qpass12_kernel<<<6656, 256, 0, stream>>>(Bf, cs12 + 13 * 144, A);
    q4_kernel<<<16, 64, 0, stream>>>(Bf, cs4, A);
    gn1_kernel<<<1024, 160, 0, stream>>>(A, x, gn1s, gn1b, out);
}

// Round 6
// 801.346 us; speedup vs baseline: 2.9543x; 1.1232x over previous
//
#include <hip/hip_runtime.h>
#include <math.h>

// ---------------------------------------------------------------------------
// QFullResnetBlock: two quantum passes (13x 12-qubit sims + 1x 4-qubit sim per
// batch elem) + groupnorm/time-FiLM/swish glue + residual.
//
// 12-qubit sim: TWO waves per sim, 32 amps per thread; 2 sims per 256-thread
// workgroup. Amplitude index amp (12 bits) = (wv << 11) | (lane << 5) | k :
//   bits 0..4  = k    (register-local, sr[32]/si[32] = 64 VGPR state)
//   bits 5..10 = lane (lane bit L = amp bit 5+L; exchange via __shfl_xor or
//                      v_permlane{16,32}_swap for L=4,5)
//   bit  11    = wv   (wave within sim; exchange via LDS, 1 CRX per layer)
// Qubit w lives at amp bit (11-w).
//
// REGISTER ALLOCATION (R1-R5): __launch_bounds__(256) + amdgpu_waves_per_eu
// with an explicit (min,max) allocates exactly the body's demand (R5: 104
// VGPR, zero scratch). Min-only bounds chase 2x min occupancy and spill the
// whole temp set (R1: 465 MB, R4: 3.9 GB scratch write-back). max=4 lifts the
// R5 occupancy cap (22.8% ~ 1.8 waves/SIMD) to the 4/SIMD that VGPR=104 and
// LDS=33.8KB both permit.
//
// DS-PIPE PRESSURE (R5): ~288 ds ops/thread/layer ~ 220 us/dispatch on the
// one LDS pipe per CU vs a 291 us VALU floor -> co-bottleneck. The mask-16 /
// mask-32 shuffle gates are moved to VALU via the permlane double-swap:
//   swap(a,b); swap(b,a)  ==>  a = shfl_xor(b0,M), b = shfl_xor(a0,M)
// (holds for either half-orientation of v_permlane*_swap_b32).
//
// Gate pattern per layer l, group j, m=0..3 (amp-bit positions):
//   crz/crx target bit pt = 4j+m, control bit pc = (4j+8+m)%12
//   j=0: pt=m (k, local pairs); pc=8+m -> lane bits 3,4,5 (m<3), wv (m=3)
//   j=1: pt=4+m -> k bit 4 (m=0), lane bits 0..2 (m>=1); pc=m (k, free skip)
//   j=2: pt=8+m -> lane bits 3,4,5 (m<3), wv (m=3 -> LDS); pc=4+m -> k bit 4
//        (m=0), lane bits 0..2 (m>=1, thread-uniform)
// ---------------------------------------------------------------------------

#define PI_F 3.14159265358979323846f

// CRZ, control = k bit PC, target = k bit PT
template<int PC, int PT>
__device__ __forceinline__ void crz_kk(float cg, float sg, float* sr, float* si)
{
#pragma unroll
    for (int k = 0; k < 32; ++k) {
        if (!((k >> PC) & 1)) continue;
        float ss = ((k >> PT) & 1) ? sg : -sg;
        float r = sr[k], im = si[k];
        sr[k] = cg * r  - ss * im;
        si[k] = cg * im + ss * r;
    }
}

// CRZ, control = k bit PC, target = lane bit LT (sign hoisted per thread)
template<int PC, int LT>
__device__ __forceinline__ void crz_kl(float cg, float sg, float* sr, float* si,
                                       int lane)
{
    float ss = ((lane >> LT) & 1) ? sg : -sg;
#pragma unroll
    for (int k = 0; k < 32; ++k) {
        if (!((k >> PC) & 1)) continue;
        float r = sr[k], im = si[k];
        sr[k] = cg * r  - ss * im;
        si[k] = cg * im + ss * r;
    }
}

// CRX, control folded into (cg,sg) [identity when inactive], target = k bit PT
template<int PT>
__device__ __forceinline__ void crx_loc(float cg, float sg, float* sr, float* si)
{
#pragma unroll
    for (int k = 0; k < 32; ++k) {
        if ((k >> PT) & 1) continue;
        int p = k | (1 << PT);
        float r0 = sr[k], i0 = si[k], r1 = sr[p], i1 = si[p];
        sr[k] = cg * r0 + sg * i1;  si[k] = cg * i0 - sg * r1;
        sr[p] = cg * r1 + sg * i0;  si[p] = cg * i1 - sg * r0;
    }
}

// CRX, control = k bit PC, target = k bit PT
template<int PC, int PT>
__device__ __forceinline__ void crx_kk(float cg, float sg, float* sr, float* si)
{
#pragma unroll
    for (int k = 0; k < 32; ++k) {
        if (!((k >> PC) & 1) || ((k >> PT) & 1)) continue;
        int p = k | (1 << PT);
        float r0 = sr[k], i0 = si[k], r1 = sr[p], i1 = si[p];
        sr[k] = cg * r0 + sg * i1;  si[k] = cg * i0 - sg * r1;
        sr[p] = cg * r1 + sg * i0;  si[p] = cg * i1 - sg * r0;
    }
}

// CRX, control = k bit PC (compile-time skip), target = lane bit LT (shuffle)
template<int PC, int LT>
__device__ __forceinline__ void crx_sh_k(float cg, float sg, float* sr, float* si)
{
#pragma unroll
    for (int k = 0; k < 32; ++k) {
        if (!((k >> PC) & 1)) continue;
        float br = __shfl_xor(sr[k], 1 << LT, 64);
        float bi = __shfl_xor(si[k], 1 << LT, 64);
        float r = sr[k], im = si[k];
        sr[k] = cg * r  + sg * bi;
        si[k] = cg * im - sg * br;
    }
}

// CRX, control folded (thread-uniform), target = lane bit LT in {4,5}.
// Cross-lane exchange on the VALU pipe via permlane double-swap (all lanes
// active here; no exec-mask hazard). After the two swaps:
//   a = shfl_xor(si[k], 1<<LT)  (bi),  b = shfl_xor(sr[k], 1<<LT)  (br)
template<int LT>
__device__ __forceinline__ void crx_perm_all(float cg, float sg, float* sr, float* si)
{
#pragma unroll
    for (int k = 0; k < 32; ++k) {
        float a = sr[k], b = si[k];
        if constexpr (LT == 4) {
            asm("v_permlane16_swap_b32 %0, %1\n\t"
                "v_permlane16_swap_b32 %1, %0"
                : "+v"(a), "+v"(b));
        } else {
            asm("v_permlane32_swap_b32 %0, %1\n\t"
                "v_permlane32_swap_b32 %1, %0"
                : "+v"(a), "+v"(b));
        }
        float r = sr[k], im = si[k];
        sr[k] = cg * r  + sg * a;
        si[k] = cg * im - sg * b;
    }
}

// Fused j=0 CRZ group: gates m=0..3; ctrl = lane bits 3,4,5 (m<3) / wv (m=3),
// all thread-uniform; target = k bit m. Multiplier depends only on k&15;
// M[15-t] = conj(M[t]) -> 8-entry complex table.
__device__ __forceinline__ void crz_j0_fused(const float* a, float* sr, float* si,
                                             int lane, int wv)
{
    float gr[4], gi[4];
#pragma unroll
    for (int m = 0; m < 4; ++m) {
        bool cb = (m < 3) ? ((lane >> (3 + m)) & 1) : (wv != 0);
        gr[m] = cb ? a[2 * m]     : 1.0f;
        gi[m] = cb ? a[2 * m + 1] : 0.0f;
    }
    // pair products with conjugate symmetry: store [t1t0]=00 and 01
    float u0 = gr[1] * gr[0], v0 = gi[1] * gi[0];
    float w0 = gr[1] * gi[0], z0 = gi[1] * gr[0];
    float p01r[2] = { u0 - v0, u0 + v0 };
    float p01i[2] = { -(w0 + z0), w0 - z0 };
    float u1 = gr[3] * gr[2], v1 = gi[3] * gi[2];
    float w1 = gr[3] * gi[2], z1 = gi[3] * gr[2];
    float p23r[2] = { u1 - v1, u1 + v1 };
    float p23i[2] = { -(w1 + z1), w1 - z1 };

    float Mr[8], Mi[8];
#pragma unroll
    for (int t = 0; t < 8; ++t) {
        const int t10 = t & 3, t2 = (t >> 2) & 1;
        float br = (t10 == 0 || t10 == 3) ? p01r[0] : p01r[1];
        float bi = (t10 == 0) ? p01i[0] : (t10 == 1) ? p01i[1]
                 : (t10 == 2) ? -p01i[1] : -p01i[0];
        float ar = p23r[t2], ai = p23i[t2];
        Mr[t] = ar * br - ai * bi;
        Mi[t] = ar * bi + ai * br;
    }
#pragma unroll
    for (int k = 0; k < 32; ++k) {
        const int t = k & 15;
        float mr = (t < 8) ? Mr[t] : Mr[15 - t];
        float mi = (t < 8) ? Mi[t] : -Mi[15 - t];
        float r = sr[k], im = si[k];
        sr[k] = mr * r  - mi * im;
        si[k] = mr * im + mi * r;
    }
}

// Fused j=2 CRZ group (coeffs a[0..7] = layer base + 32):
//  m=0: ctrl k bit 4,   sign lane bit 3
//  m=1: ctrl lane bit 0, sign lane bit 4   (thread-uniform)
//  m=2: ctrl lane bit 1, sign lane bit 5   (thread-uniform)
//  m=3: ctrl lane bit 2, sign wv           (thread-uniform)
// Multiplier depends only on k bit 4 -> 2-entry table.
__device__ __forceinline__ void crz_j2_fused(const float* a, float* sr, float* si,
                                             int lane, int wv)
{
    float s0p = ((lane >> 3) & 1) ? a[1] : -a[1];
    bool cb1 = lane & 1;
    float sg1 = ((lane >> 4) & 1) ? a[3] : -a[3];
    float g1r = cb1 ? a[2] : 1.0f, g1i = cb1 ? sg1 : 0.0f;
    bool cb2 = (lane >> 1) & 1;
    float sg2 = ((lane >> 5) & 1) ? a[5] : -a[5];
    float g2r = cb2 ? a[4] : 1.0f, g2i = cb2 ? sg2 : 0.0f;
    bool cb3 = (lane >> 2) & 1;
    float sg3 = wv ? a[7] : -a[7];
    float g3r = cb3 ? a[6] : 1.0f, g3i = cb3 ? sg3 : 0.0f;
    float t12r = g1r * g2r - g1i * g2i, t12i = g1r * g2i + g1i * g2r;
    float Sr  = t12r * g3r - t12i * g3i;
    float Si_ = t12r * g3i + t12i * g3r;
    float T1r = Sr * a[0] - Si_ * s0p;
    float T1i = Sr * s0p + Si_ * a[0];
#pragma unroll
    for (int k = 0; k < 32; ++k) {
        float tr = (k >> 4) ? T1r : Sr;
        float ti = (k >> 4) ? T1i : Si_;
        float r = sr[k], im = si[k];
        sr[k] = tr * r  - ti * im;
        si[k] = tr * im + ti * r;
    }
}

__global__ void __launch_bounds__(256)
__attribute__((amdgpu_waves_per_eu(2, 4)))
qpass12_kernel(const float* __restrict__ inp, const float* __restrict__ cs,
               float* __restrict__ outp)
{
    // exchange buffer: [sim][wv][ai 0..31][66] floats, stride 66 -> 2-way banks
    __shared__ float xbuf[2 * 2 * 32 * 66];   // 33792 B
    const int tid  = threadIdx.x;
    const int simL = tid >> 7;            // sim within WG (0,1)
    const int ts   = tid & 127;           // thread within sim
    const int wv   = ts >> 6;             // amp bit 11
    const int lane = ts & 63;             // amp bits 5..10
    const int sim  = blockIdx.x * 2 + simL;
    const int ci = sim % 13;
    const int b  = sim / 13;
    const float* csc = cs + ci * 144;     // 72 gates * (cos,sin)
    const int ibase = b * 160 + ci * 3;   // (B,2,2,40) flat; sp stride 40

    // data angles: qubit w <- inp[b, w/3, (w%3)+3*ci]
    float cw[12], sw[12];
#pragma unroll
    for (int w = 0; w < 12; ++w) {
        float x = inp[ibase + (w / 3) * 40 + (w % 3)];
        __sincosf(0.5f * x, &sw[w], &cw[w]);
    }

    // product-state init: qubit w at amp bit 11-w.
    // thread-uniform prefactor: qubit 0 <- wv; qubits 1..6 <- lane bit 6-w
    float pref = wv ? sw[0] : cw[0];
#pragma unroll
    for (int w = 1; w < 7; ++w)
        pref *= ((lane >> (6 - w)) & 1) ? sw[w] : cw[w];

    // k tables: fb over k bits 0..2 (qubits 11,10,9), eb over bits 3..4 (8,7)
    float fb[8], eb[4];
#pragma unroll
    for (int t = 0; t < 8; ++t)
        fb[t] = ((t & 1) ? sw[11] : cw[11]) * ((t & 2) ? sw[10] : cw[10]) *
                ((t & 4) ? sw[9] : cw[9]);
#pragma unroll
    for (int t = 0; t < 4; ++t)
        eb[t] = pref * ((t & 1) ? sw[8] : cw[8]) * ((t & 2) ? sw[7] : cw[7]);

    // phase (-i)^popc(amp)
    const int pl = (__popc(lane) + wv) & 3;
    float oa = (pl == 0) ? 1.0f : (pl == 2) ? -1.0f : 0.0f;
    float ob = (pl == 1) ? -1.0f : (pl == 3) ? 1.0f : 0.0f;

    float sr[32], si[32];
#pragma unroll
    for (int k = 0; k < 32; ++k) {
        float v = eb[k >> 3] * fb[k & 7];
        const int q = __popc(k) & 3;
        if (q == 0)      { sr[k] =  v * oa; si[k] =  v * ob; }
        else if (q == 1) { sr[k] =  v * ob; si[k] = -v * oa; }
        else if (q == 2) { sr[k] = -v * oa; si[k] = -v * ob; }
        else             { sr[k] = -v * ob; si[k] =  v * oa; }
    }

    // cross-wave exchange addressing (j=2 m=3 CRX: ctrl = lane bit 2)
    const bool act = (lane >> 2) & 1;
    const int  ai  = ((lane >> 3) << 2) | (lane & 3);   // compress free bits
    float* xw = &xbuf[(((simL << 1) | wv) * 32 + ai) * 66];
    float* xr = &xbuf[(((simL << 1) | (wv ^ 1)) * 32 + ai) * 66];

#pragma unroll 1
    for (int l = 0; l < 3; ++l) {
        const float* a = csc + l * 48;

        // ---- group j=0: tgt k bits 0..3; ctrl lane 3,4,5 / wv (uniform) ----
        crz_j0_fused(a, sr, si, lane, wv);
        { bool cb = (lane >> 3) & 1;
          crx_loc<0>(cb ? a[ 8] : 1.0f, cb ? a[ 9] : 0.0f, sr, si); }
        { bool cb = (lane >> 4) & 1;
          crx_loc<1>(cb ? a[10] : 1.0f, cb ? a[11] : 0.0f, sr, si); }
        { bool cb = (lane >> 5) & 1;
          crx_loc<2>(cb ? a[12] : 1.0f, cb ? a[13] : 0.0f, sr, si); }
        { bool cb = wv != 0;
          crx_loc<3>(cb ? a[14] : 1.0f, cb ? a[15] : 0.0f, sr, si); }

        // ---- group j=1: tgt k bit 4 / lane 0..2; ctrl k bits 0..3 ----
        crz_kk<0, 4>(a[16], a[17], sr, si);
        crz_kl<1, 0>(a[18], a[19], sr, si, lane);
        crz_kl<2, 1>(a[20], a[21], sr, si, lane);
        crz_kl<3, 2>(a[22], a[23], sr, si, lane);
        crx_kk<0, 4>(a[24], a[25], sr, si);
        crx_sh_k<1, 0>(a[26], a[27], sr, si);
        crx_sh_k<2, 1>(a[28], a[29], sr, si);
        crx_sh_k<3, 2>(a[30], a[31], sr, si);

        // ---- group j=2: tgt lane 3,4,5 / wv; ctrl k bit 4 / lane 0..2 ----
        crz_j2_fused(a + 32, sr, si, lane, wv);
        crx_sh_k<4, 3>(a[40], a[41], sr, si);
        { bool cb = lane & 1;
          crx_perm_all<4>(cb ? a[42] : 1.0f, cb ? a[43] : 0.0f, sr, si); }
        { bool cb = (lane >> 1) & 1;
          crx_perm_all<5>(cb ? a[44] : 1.0f, cb ? a[45] : 0.0f, sr, si); }
        // m=3: cross-wave CRX (tgt wv), ctrl lane bit 2 (same for partner)
        __syncthreads();
        if (act) {
#pragma unroll
            for (int k = 0; k < 32; ++k) {
                xw[2 * k]     = sr[k];
                xw[2 * k + 1] = si[k];
            }
        }
        __syncthreads();
        if (act) {
            float cg = a[46], sg = a[47];
#pragma unroll
            for (int k = 0; k < 32; ++k) {
                float br = xr[2 * k], bi = xr[2 * k + 1];
                float r = sr[k], im = si[k];
                sr[k] = cg * r  + sg * bi;
                si[k] = cg * im - sg * br;
            }
        }
    }

    // expectation values <Z_w>; reuse sr[] as probability array
    float total = 0.0f;
#pragma unroll
    for (int k = 0; k < 32; ++k) {
        sr[k] = sr[k] * sr[k] + si[k] * si[k];
        total += sr[k];
    }
    float v12[12];
    v12[0] = wv ? -total : total;
#pragma unroll
    for (int w = 1; w < 7; ++w)
        v12[w] = ((lane >> (6 - w)) & 1) ? -total : total;
#pragma unroll
    for (int w = 7; w < 12; ++w) {
        float acc = 0.0f;
#pragma unroll
        for (int k = 0; k < 32; ++k)
            acc += ((k >> (11 - w)) & 1) ? -sr[k] : sr[k];
        v12[w] = acc;
    }
    // in-wave butterfly reduce (64 lanes)
#pragma unroll
    for (int w = 0; w < 12; ++w) {
#pragma unroll
        for (int off = 1; off < 64; off <<= 1)
            v12[w] += __shfl_xor(v12[w], off, 64);
    }
    // cross-wave combine via LDS (reuse xbuf; barrier protects last exchange)
    __syncthreads();
    if (lane == 0) {
#pragma unroll
        for (int w = 0; w < 12; ++w)
            xbuf[((simL << 1) | wv) * 12 + w] = v12[w];
    }
    __syncthreads();
    if (ts < 12) {
        float z = xbuf[(simL << 1) * 12 + ts] +
                  xbuf[((simL << 1) | 1) * 12 + ts];
        outp[ibase + (ts / 3) * 40 + (ts % 3)] = z;
    }
}

__global__ void q4_kernel(const float* __restrict__ inp,
                          const float* __restrict__ cs4,
                          float* __restrict__ outp)
{
    int b = blockIdx.x * blockDim.x + threadIdx.x;
    if (b >= 1024) return;
    float cw[4], sw[4];
#pragma unroll
    for (int j = 0; j < 4; ++j) {
        float x = inp[(b * 4 + j) * 40 + 39];
        __sincosf(0.5f * x, &sw[j], &cw[j]);
    }
    float sr[16], si[16];
#pragma unroll
    for (int k = 0; k < 16; ++k) {
        float v = 1.0f;
#pragma unroll
        for (int j = 0; j < 4; ++j)
            v *= ((k >> (3 - j)) & 1) ? sw[j] : cw[j];
        int ph = __popc(k) & 3;
        sr[k] = (ph == 0) ? v : (ph == 2) ? -v : 0.0f;
        si[k] = (ph == 1) ? -v : (ph == 3) ? v : 0.0f;
    }
#pragma unroll
    for (int l = 0; l < 4; ++l) {
        // RX(theta[4l+w]) on qubit w (bit 3-w)
#pragma unroll
        for (int w = 0; w < 4; ++w) {
            float cg = cs4[2 * (4 * l + w)], sg = cs4[2 * (4 * l + w) + 1];
            const int m = 1 << (3 - w);
#pragma unroll
            for (int k = 0; k < 16; ++k) {
                if (k & m) continue;
                int p2 = k | m;
                float r0 = sr[k], i0 = si[k], r1 = sr[p2], i1 = si[p2];
                sr[k]  = cg * r0 + sg * i1;  si[k]  = cg * i0 - sg * r1;
                sr[p2] = cg * r1 + sg * i0;  si[p2] = cg * i1 - sg * r0;
            }
        }
        // CNOT (0,1),(1,2),(2,3),(3,0)
#pragma unroll
        for (int e = 0; e < 4; ++e) {
            const int cq = e, tq = (e + 1) & 3;
            const int pcb = 1 << (3 - cq), ptb = 1 << (3 - tq);
#pragma unroll
            for (int k = 0; k < 16; ++k) {
                if (!(k & pcb)) continue;
                if (k & ptb) continue;
                int p2 = k | ptb;
                float tr = sr[k], ti = si[k];
                sr[k] = sr[p2]; si[k] = si[p2];
                sr[p2] = tr;    si[p2] = ti;
            }
        }
    }
    float p[16];
#pragma unroll
    for (int k = 0; k < 16; ++k) p[k] = sr[k] * sr[k] + si[k] * si[k];
#pragma unroll
    for (int j = 0; j < 4; ++j) {
        float z = 0.0f;
#pragma unroll
        for (int k = 0; k < 16; ++k)
            z += ((k >> (3 - j)) & 1) ? -p[k] : p[k];
        outp[(b * 4 + j) * 40 + 39] = z;
    }
}

__global__ void prep_kernel(const float* __restrict__ q12,
                            const float* __restrict__ q4,
                            float* __restrict__ cs12,
                            float* __restrict__ cs4)
{
    int idx = blockIdx.x * 256 + threadIdx.x;
    if (idx < 26 * 72) {
        // gate angle = 2*pi*p, half-angle = pi*p
        float s, c;
        sincosf(PI_F * q12[idx], &s, &c);
        cs12[2 * idx]     = c;
        cs12[2 * idx + 1] = s;
    }
    if (idx < 16) {
        float s, c;
        sincosf(0.5f * q4[idx], &s, &c);
        cs4[2 * idx]     = c;
        cs4[2 * idx + 1] = s;
    }
}

__global__ void tmlp_kernel(const float* __restrict__ emb,
                            const float* __restrict__ W,
                            const float* __restrict__ bias,
                            float* __restrict__ t)
{
    __shared__ float se[128];
    int b = blockIdx.x, tid = threadIdx.x;
    float e = emb[b * 128 + tid];
    se[tid] = e / (1.0f + __expf(-e));
    __syncthreads();
    if (tid < 80) {
        float acc = bias[tid];
        for (int k = 0; k < 128; ++k) acc += se[k] * W[k * 80 + tid];
        t[b * 80 + tid] = acc;
    }
}

__global__ void gn0_kernel(const float* __restrict__ h, const float* __restrict__ t,
                           const float* __restrict__ sc, const float* __restrict__ bi,
                           float* __restrict__ outp)
{
    __shared__ float v[160];
    __shared__ float mu[10], rstd[10];
    int b = blockIdx.x, tid = threadIdx.x;
    if (tid < 160) v[tid] = h[b * 160 + tid];
    __syncthreads();
    if (tid < 10) {
        float s1 = 0.0f, s2 = 0.0f;
#pragma unroll
        for (int sp = 0; sp < 4; ++sp)
#pragma unroll
            for (int k = 0; k < 4; ++k) {
                float x = v[sp * 40 + tid * 4 + k];
                s1 += x; s2 += x * x;
            }
        float m = s1 * (1.0f / 16.0f);
        float var = s2 * (1.0f / 16.0f) - m * m;
        mu[tid] = m; rstd[tid] = rsqrtf(var + 1e-6f);
    }
    __syncthreads();
    if (tid < 160) {
        int ch = tid % 40;
        int g = ch >> 2;
        float hn = (v[tid] - mu[g]) * rstd[g] * sc[ch] + bi[ch];
        float scale = t[b * 80 + ch], shift = t[b * 80 + 40 + ch];
        float z = hn * (1.0f + scale) + shift;
        outp[b * 160 + tid] = z / (1.0f + __expf(-z));
    }
}

__global__ void gn1_kernel(const float* __restrict__ h, const float* __restrict__ x,
                           const float* __restrict__ sc, const float* __restrict__ bi,
                           float* __restrict__ outp)
{
    __shared__ float v[160];
    __shared__ float mu[10], rstd[10];
    int b = blockIdx.x, tid = threadIdx.x;
    if (tid < 160) v[tid] = h[b * 160 + tid];
    __syncthreads();
    if (tid < 10) {
        float s1 = 0.0f, s2 = 0.0f;
#pragma unroll
        for (int sp = 0; sp < 4; ++sp)
#pragma unroll
            for (int k = 0; k < 4; ++k) {
                float xx = v[sp * 40 + tid * 4 + k];
                s1 += xx; s2 += xx * xx;
            }
        float m = s1 * (1.0f / 16.0f);
        float var = s2 * (1.0f / 16.0f) - m * m;
        mu[tid] = m; rstd[tid] = rsqrtf(var + 1e-6f);
    }
    __syncthreads();
    if (tid < 160) {
        int ch = tid % 40;
        int g = ch >> 2;
        float hn = (v[tid] - mu[g]) * rstd[g] * sc[ch] + bi[ch];
        float sws = hn / (1.0f + __expf(-hn));
        outp[b * 160 + tid] = x[b * 160 + tid] + sws;
    }
}

extern "C" void kernel_launch(void* const* d_in, const int* in_sizes, int n_in,
                              void* d_out, int out_size, void* d_ws, size_t ws_size,
                              hipStream_t stream)
{
    const float* x    = (const float*)d_in[0];
    const float* temb = (const float*)d_in[1];
    const float* q12  = (const float*)d_in[2];
    const float* q4   = (const float*)d_in[3];
    const float* gn0s = (const float*)d_in[4];
    const float* gn0b = (const float*)d_in[5];
    const float* gn1s = (const float*)d_in[6];
    const float* gn1b = (const float*)d_in[7];
    const float* tw   = (const float*)d_in[8];
    const float* tb   = (const float*)d_in[9];
    float* out = (float*)d_out;

    float* ws   = (float*)d_ws;
    float* cs12 = ws;               // 26*72*2   = 3744
    float* cs4  = cs12 + 3744;      // 32
    float* tbuf = cs4 + 32;         // 1024*80   = 81920
    float* A    = tbuf + 81920;     // 1024*160  = 163840 (raw qpass out)
    float* Bf   = A + 163840;       // 1024*160  = 163840 (gn0 out / qpass2 in)

    prep_kernel<<<8, 256, 0, stream>>>(q12, q4, cs12, cs4);
    tmlp_kernel<<<1024, 128, 0, stream>>>(temb, tw, tb, tbuf);

    // pass 1  (6656 blocks x 2 sims x 2 waves = 13312 sims)
    qpass12_kernel<<<6656, 256, 0, stream>>>(x, cs12, A);
    q4_kernel<<<16, 64, 0, stream>>>(x, cs4, A);
    gn0_kernel<<<1024, 160, 0, stream>>>(A, tbuf, gn0s, gn0b, Bf);

    // pass 2
    qpass12_kernel<<<6656, 256, 0, stream>>>(Bf, cs12 + 13 * 144, A);
    q4_kernel<<<16, 64, 0, stream>>>(Bf, cs4, A);
    gn1_kernel<<<1024, 160, 0, stream>>>(A, x, gn1s, gn1b, out);
}

// Round 7
// 642.076 us; speedup vs baseline: 3.6871x; 1.2481x over previous
//
#include <hip/hip_runtime.h>
#include <math.h>

// ---------------------------------------------------------------------------
// QFullResnetBlock: two quantum passes (13x 12-qubit sims + 1x 4-qubit sim per
// batch elem) + groupnorm/time-FiLM/swish glue + residual.
//
// 12-qubit sim: TWO waves per sim, 32 amps per thread held as PACKED-FP32
// pairs: f2 R[16], I[16] (f2 = ext_vector_type(2) float -> v_pk_fma_f32 class
// codegen, 2 FP32 ops/instr). 2 sims per 256-thread workgroup.
// Amplitude index amp (12 bits) = (wv << 11) | (lane << 5) | (j << 1) | e :
//   bit  0     = e    (intra-pair: element of the f2)
//   bits 1..4  = j    (16 register pairs)
//   bits 5..10 = lane (lane bit L = amp bit 5+L; ds_swizzle for L=0..3,
//                      v_permlane{16,32}_swap for L=4,5)
//   bit  11    = wv   (wave within sim; LDS b64 exchange, 1 CRX per layer)
// Qubit w lives at amp bit (11-w).
//
// REGISTER ALLOCATION (R1-R6): __launch_bounds__(256) + amdgpu_waves_per_eu
// (min,max) allocates the body's demand (R5/R6: 104/108 VGPR, zero scratch).
// Min-only launch_bounds chases 2x min occupancy and spills everything
// (R1: 465 MB, R4: 3.9 GB scratch write-back). Occupancy is pinned at ~2
// WGs/CU regardless of max (R5 vs R6) -> the remaining lever is VALU
// instruction count, addressed here with packed math (R6: VALUBusy 74%).
//
// Gate pattern per layer l, group g, m=0..3 (amp-bit positions):
//   target bit pt = 4g+m, control bit pc = (4g+8+m)%12
//   g=0: pt = pair/j0/j1/j2 ; pc = lane 3,4,5 (m<3), wv (m=3)  [uniform folds]
//   g=1: pt = j3 (m=0), lane 0..2 ; pc = pair (m=0), j0..j2 (element masks)
//   g=2: pt = lane 3,4,5, wv(m=3->LDS) ; pc = j3 (m=0), lane 0..2 (uniform)
// ---------------------------------------------------------------------------

#define PI_F 3.14159265358979323846f

typedef float f2 __attribute__((ext_vector_type(2)));

__device__ __forceinline__ f2 shfl2(f2 v, int mask)
{
    f2 r;
    r[0] = __shfl_xor(v[0], mask, 64);
    r[1] = __shfl_xor(v[1], mask, 64);
    return r;
}

// CRZ on elements with j bit CB set; full-pair multiplier (cg, ss) [ss is the
// sign-resolved sin, thread-uniform]
template<int CB>
__device__ __forceinline__ void crz_ctrlj(float cg, float ss, f2* R, f2* I)
{
#pragma unroll
    for (int j = 0; j < 16; ++j) {
        if (!((j >> CB) & 1)) continue;
        f2 r = R[j], im = I[j];
        R[j] = cg * r - ss * im;
        I[j] = cg * im + ss * r;
    }
}

// CRZ, control = pair bit (hi element only), target = j bit 3
__device__ __forceinline__ void crz_pairhi_t4(float cg, float sg, f2* R, f2* I)
{
    const f2 mrv = {1.0f, cg};
#pragma unroll
    for (int j = 0; j < 16; ++j) {
        f2 miv = {0.0f, (j & 8) ? sg : -sg};
        f2 r = R[j], im = I[j];
        R[j] = mrv * r - miv * im;
        I[j] = mrv * im + miv * r;
    }
}

// CRX within the pair (target = pair bit), uniform folded coeff
__device__ __forceinline__ void crx_pair(float cg, float sg, f2* R, f2* I)
{
#pragma unroll
    for (int j = 0; j < 16; ++j) {
        f2 r = R[j], im = I[j];
        f2 rs = __builtin_shufflevector(r, r, 1, 0);
        f2 is = __builtin_shufflevector(im, im, 1, 0);
        R[j] = cg * r + sg * is;
        I[j] = cg * im - sg * rs;
    }
}

// CRX between elements j and j|M (target = j bit log2(M)), uniform coeff
template<int M>
__device__ __forceinline__ void crx_elem(float cg, float sg, f2* R, f2* I)
{
#pragma unroll
    for (int j = 0; j < 16; ++j) {
        if (j & M) continue;
        const int p = j | M;
        f2 r0 = R[j], i0 = I[j], r1 = R[p], i1 = I[p];
        R[j] = cg * r0 + sg * i1;  I[j] = cg * i0 - sg * r1;
        R[p] = cg * r1 + sg * i0;  I[p] = cg * i1 - sg * r0;
    }
}

// CRX, control = pair bit (hi only), target = j bit 3: masked coeff vectors
__device__ __forceinline__ void crx_pairhi_t4(float cg, float sg, f2* R, f2* I)
{
    const f2 cgv = {1.0f, cg};
    const f2 sgv = {0.0f, sg};
#pragma unroll
    for (int j = 0; j < 8; ++j) {
        const int p = j + 8;
        f2 r0 = R[j], i0 = I[j], r1 = R[p], i1 = I[p];
        R[j] = cgv * r0 + sgv * i1;  I[j] = cgv * i0 - sgv * r1;
        R[p] = cgv * r1 + sgv * i0;  I[p] = cgv * i1 - sgv * r0;
    }
}

// CRX, control = j bit CB (element mask), target = lane bit LT (ds_swizzle)
template<int CB, int LT>
__device__ __forceinline__ void crx_shj(float cg, float sg, f2* R, f2* I)
{
#pragma unroll
    for (int j = 0; j < 16; ++j) {
        if (!((j >> CB) & 1)) continue;
        f2 br = shfl2(R[j], 1 << LT);
        f2 bi = shfl2(I[j], 1 << LT);
        f2 r = R[j], im = I[j];
        R[j] = cg * r + sg * bi;
        I[j] = cg * im - sg * br;
    }
}

// CRX, uniform folded ctrl, target = lane bit LT in {4,5} via permlane
// double-swap on the VALU pipe (R6-verified semantics):
//   swap(a,b); swap(b,a)  ==>  a = shfl_xor(b0,M), b = shfl_xor(a0,M)
template<int LT>
__device__ __forceinline__ void crx_perm_allv(float cg, float sg, f2* R, f2* I)
{
#pragma unroll
    for (int j = 0; j < 16; ++j) {
        float a0 = R[j][0], b0 = I[j][0];
        float a1 = R[j][1], b1 = I[j][1];
        if constexpr (LT == 4) {
            asm("v_permlane16_swap_b32 %0, %1\n\t"
                "v_permlane16_swap_b32 %1, %0" : "+v"(a0), "+v"(b0));
            asm("v_permlane16_swap_b32 %0, %1\n\t"
                "v_permlane16_swap_b32 %1, %0" : "+v"(a1), "+v"(b1));
        } else {
            asm("v_permlane32_swap_b32 %0, %1\n\t"
                "v_permlane32_swap_b32 %1, %0" : "+v"(a0), "+v"(b0));
            asm("v_permlane32_swap_b32 %0, %1\n\t"
                "v_permlane32_swap_b32 %1, %0" : "+v"(a1), "+v"(b1));
        }
        f2 A = {a0, a1}, Bv = {b0, b1};
        f2 r = R[j], im = I[j];
        R[j] = cg * r + sg * A;
        I[j] = cg * im - sg * Bv;
    }
}

// Fused g=0 CRZ group: ctrl lane bits 3,4,5 (m<3) / wv (m=3), all uniform;
// target = amp bits 0..3. Scalar 8-entry conj-symmetric table (as R4),
// expanded to a 16-entry f2 table at the use site (t = amp bits 0..3 does not
// involve j bit 3, so index = j&7 with pair (2jj, 2jj+1)).
__device__ __forceinline__ void crz_g0_fused(const float* a, f2* R, f2* I,
                                             int lane, int wv)
{
    float gr[4], gi[4];
#pragma unroll
    for (int m = 0; m < 4; ++m) {
        bool cb = (m < 3) ? ((lane >> (3 + m)) & 1) : (wv != 0);
        gr[m] = cb ? a[2 * m]     : 1.0f;
        gi[m] = cb ? a[2 * m + 1] : 0.0f;
    }
    float u0 = gr[1] * gr[0], v0 = gi[1] * gi[0];
    float w0 = gr[1] * gi[0], z0 = gi[1] * gr[0];
    float p01r[2] = { u0 - v0, u0 + v0 };
    float p01i[2] = { -(w0 + z0), w0 - z0 };
    float u1 = gr[3] * gr[2], v1 = gi[3] * gi[2];
    float w1 = gr[3] * gi[2], z1 = gi[3] * gr[2];
    float p23r[2] = { u1 - v1, u1 + v1 };
    float p23i[2] = { -(w1 + z1), w1 - z1 };

    float Mr[8], Mi[8];
#pragma unroll
    for (int t = 0; t < 8; ++t) {
        const int t10 = t & 3, t2 = (t >> 2) & 1;
        float br = (t10 == 0 || t10 == 3) ? p01r[0] : p01r[1];
        float bi = (t10 == 0) ? p01i[0] : (t10 == 1) ? p01i[1]
                 : (t10 == 2) ? -p01i[1] : -p01i[0];
        float ar = p23r[t2], ai = p23i[t2];
        Mr[t] = ar * br - ai * bi;
        Mi[t] = ar * bi + ai * br;
    }
#pragma unroll
    for (int j = 0; j < 16; ++j) {
        const int jj = j & 7;
        f2 mr, mi;
        if (jj < 4) {
            mr = f2{ Mr[2 * jj],      Mr[2 * jj + 1] };
            mi = f2{ Mi[2 * jj],      Mi[2 * jj + 1] };
        } else {
            mr = f2{ Mr[15 - 2 * jj], Mr[14 - 2 * jj] };
            mi = f2{ -Mi[15 - 2 * jj], -Mi[14 - 2 * jj] };
        }
        f2 r = R[j], im = I[j];
        R[j] = mr * r - mi * im;
        I[j] = mr * im + mi * r;
    }
}

// Fused g=2 CRZ group (coeffs a[0..7] = layer base + 32):
//  m=0: ctrl j bit 3, sign lane bit 3 ; m=1: ctrl lane 0, sign lane 4
//  m=2: ctrl lane 1, sign lane 5 ; m=3: ctrl lane 2, sign wv
// Multiplier depends only on j bit 3 -> 2 complex values.
__device__ __forceinline__ void crz_g2_fused(const float* a, f2* R, f2* I,
                                             int lane, int wv)
{
    float s0p = ((lane >> 3) & 1) ? a[1] : -a[1];
    bool cb1 = lane & 1;
    float sg1 = ((lane >> 4) & 1) ? a[3] : -a[3];
    float g1r = cb1 ? a[2] : 1.0f, g1i = cb1 ? sg1 : 0.0f;
    bool cb2 = (lane >> 1) & 1;
    float sg2 = ((lane >> 5) & 1) ? a[5] : -a[5];
    float g2r = cb2 ? a[4] : 1.0f, g2i = cb2 ? sg2 : 0.0f;
    bool cb3 = (lane >> 2) & 1;
    float sg3 = wv ? a[7] : -a[7];
    float g3r = cb3 ? a[6] : 1.0f, g3i = cb3 ? sg3 : 0.0f;
    float t12r = g1r * g2r - g1i * g2i, t12i = g1r * g2i + g1i * g2r;
    float Sr  = t12r * g3r - t12i * g3i;
    float Si_ = t12r * g3i + t12i * g3r;
    float T1r = Sr * a[0] - Si_ * s0p;
    float T1i = Sr * s0p + Si_ * a[0];
#pragma unroll
    for (int j = 0; j < 16; ++j) {
        float tr = (j & 8) ? T1r : Sr;
        float ti = (j & 8) ? T1i : Si_;
        f2 r = R[j], im = I[j];
        R[j] = tr * r - ti * im;
        I[j] = tr * im + ti * r;
    }
}

__global__ void __launch_bounds__(256)
__attribute__((amdgpu_waves_per_eu(2, 4)))
qpass12_kernel(const float* __restrict__ inp, const float* __restrict__ cs,
               float* __restrict__ outp)
{
    // exchange buffer: [sim][wv][ai 0..31] rows of 33 f2 (32 data + 1 pad):
    // b64 accesses land 2-way per bank (free). 4224 f2 = 33792 B.
    __shared__ f2 xbufv[2 * 2 * 32 * 33];
    float* xbuff = reinterpret_cast<float*>(xbufv);
    const int tid  = threadIdx.x;
    const int simL = tid >> 7;            // sim within WG (0,1)
    const int ts   = tid & 127;           // thread within sim
    const int wv   = ts >> 6;             // amp bit 11
    const int lane = ts & 63;             // amp bits 5..10
    const int sim  = blockIdx.x * 2 + simL;
    const int ci = sim % 13;
    const int b  = sim / 13;
    const float* csc = cs + ci * 144;     // 72 gates * (cos,sin)
    const int ibase = b * 160 + ci * 3;   // (B,2,2,40) flat; sp stride 40

    // data angles: qubit w <- inp[b, w/3, (w%3)+3*ci]
    float cw[12], sw[12];
#pragma unroll
    for (int w = 0; w < 12; ++w) {
        float x = inp[ibase + (w / 3) * 40 + (w % 3)];
        __sincosf(0.5f * x, &sw[w], &cw[w]);
    }

    // product-state init: qubit w at amp bit 11-w.
    float pref = wv ? sw[0] : cw[0];
#pragma unroll
    for (int w = 1; w < 7; ++w)
        pref *= ((lane >> (6 - w)) & 1) ? sw[w] : cw[w];

    // k tables: fb over amp bits 0..2 (qubits 11,10,9), eb over 3..4 (8,7)
    float fb[8], eb[4];
#pragma unroll
    for (int t = 0; t < 8; ++t)
        fb[t] = ((t & 1) ? sw[11] : cw[11]) * ((t & 2) ? sw[10] : cw[10]) *
                ((t & 4) ? sw[9] : cw[9]);
#pragma unroll
    for (int t = 0; t < 4; ++t)
        eb[t] = pref * ((t & 1) ? sw[8] : cw[8]) * ((t & 2) ? sw[7] : cw[7]);
    f2 fbv[4];
#pragma unroll
    for (int t = 0; t < 4; ++t)
        fbv[t] = f2{ fb[2 * t], fb[2 * t + 1] };

    // phase (-i)^popc(amp): per-thread (oa,ob), per-element compile-time q
    const int pl = (__popc(lane) + wv) & 3;
    float oa = (pl == 0) ? 1.0f : (pl == 2) ? -1.0f : 0.0f;
    float ob = (pl == 1) ? -1.0f : (pl == 3) ? 1.0f : 0.0f;

    f2 R[16], I[16];
#pragma unroll
    for (int j = 0; j < 16; ++j) {
        f2 v2 = eb[j >> 2] * fbv[j & 3];
        const int q0 = ((j & 1) + ((j >> 1) & 1) + ((j >> 2) & 1) + ((j >> 3) & 1)) & 3;
        const int q1 = (q0 + 1) & 3;
        const float c0l = (q0 == 0) ? oa : (q0 == 1) ? ob : (q0 == 2) ? -oa : -ob;
        const float c1l = (q0 == 0) ? ob : (q0 == 1) ? -oa : (q0 == 2) ? -ob : oa;
        const float c0h = (q1 == 0) ? oa : (q1 == 1) ? ob : (q1 == 2) ? -oa : -ob;
        const float c1h = (q1 == 0) ? ob : (q1 == 1) ? -oa : (q1 == 2) ? -ob : oa;
        R[j] = f2{ v2[0] * c0l, v2[1] * c0h };
        I[j] = f2{ v2[0] * c1l, v2[1] * c1h };
    }

    // cross-wave exchange addressing (g=2 m=3 CRX: ctrl = lane bit 2)
    const bool act = (lane >> 2) & 1;
    const int  ai  = ((lane >> 3) << 2) | (lane & 3);   // compress free bits
    f2* xw = &xbufv[(((simL << 1) | wv) * 32 + ai) * 33];
    f2* xr = &xbufv[(((simL << 1) | (wv ^ 1)) * 32 + ai) * 33];

#pragma unroll 1
    for (int l = 0; l < 3; ++l) {
        const float* a = csc + l * 48;

        // ---- group g=0: tgt amp bits 0..3; ctrl lane 3,4,5 / wv ----
        crz_g0_fused(a, R, I, lane, wv);
        { bool cb = (lane >> 3) & 1;
          crx_pair(cb ? a[ 8] : 1.0f, cb ? a[ 9] : 0.0f, R, I); }
        { bool cb = (lane >> 4) & 1;
          crx_elem<1>(cb ? a[10] : 1.0f, cb ? a[11] : 0.0f, R, I); }
        { bool cb = (lane >> 5) & 1;
          crx_elem<2>(cb ? a[12] : 1.0f, cb ? a[13] : 0.0f, R, I); }
        { bool cb = wv != 0;
          crx_elem<4>(cb ? a[14] : 1.0f, cb ? a[15] : 0.0f, R, I); }

        // ---- group g=1: tgt j bit 3 / lane 0..2; ctrl pair / j bits ----
        crz_pairhi_t4(a[16], a[17], R, I);
        { float ss = (lane & 1)        ? a[19] : -a[19]; crz_ctrlj<0>(a[18], ss, R, I); }
        { float ss = ((lane >> 1) & 1) ? a[21] : -a[21]; crz_ctrlj<1>(a[20], ss, R, I); }
        { float ss = ((lane >> 2) & 1) ? a[23] : -a[23]; crz_ctrlj<2>(a[22], ss, R, I); }
        crx_pairhi_t4(a[24], a[25], R, I);
        crx_shj<0, 0>(a[26], a[27], R, I);
        crx_shj<1, 1>(a[28], a[29], R, I);
        crx_shj<2, 2>(a[30], a[31], R, I);

        // ---- group g=2: tgt lane 3,4,5 / wv; ctrl j bit 3 / lane 0..2 ----
        crz_g2_fused(a + 32, R, I, lane, wv);
        crx_shj<3, 3>(a[40], a[41], R, I);
        { bool cb = lane & 1;
          crx_perm_allv<4>(cb ? a[42] : 1.0f, cb ? a[43] : 0.0f, R, I); }
        { bool cb = (lane >> 1) & 1;
          crx_perm_allv<5>(cb ? a[44] : 1.0f, cb ? a[45] : 0.0f, R, I); }
        // m=3: cross-wave CRX (tgt wv), ctrl lane bit 2 (same for partner)
        __syncthreads();
        if (act) {
#pragma unroll
            for (int j = 0; j < 16; ++j) {
                xw[j]      = R[j];
                xw[16 + j] = I[j];
            }
        }
        __syncthreads();
        if (act) {
            float cg = a[46], sg = a[47];
#pragma unroll
            for (int j = 0; j < 16; ++j) {
                f2 br = xr[j], bi = xr[16 + j];
                f2 r = R[j], im = I[j];
                R[j] = cg * r + sg * bi;
                I[j] = cg * im - sg * br;
            }
        }
    }

    // expectation values <Z_w>
    f2 accT = {0.0f, 0.0f}, acc7 = {0.0f, 0.0f}, acc8 = {0.0f, 0.0f};
    f2 acc9 = {0.0f, 0.0f}, acc10 = {0.0f, 0.0f};
#pragma unroll
    for (int j = 0; j < 16; ++j) {
        f2 p = R[j] * R[j] + I[j] * I[j];
        accT += p;
        if (j & 8) acc7 -= p; else acc7 += p;
        if (j & 4) acc8 -= p; else acc8 += p;
        if (j & 2) acc9 -= p; else acc9 += p;
        if (j & 1) acc10 -= p; else acc10 += p;
    }
    float total = accT[0] + accT[1];
    float v12[12];
    v12[0] = wv ? -total : total;
#pragma unroll
    for (int w = 1; w < 7; ++w)
        v12[w] = ((lane >> (6 - w)) & 1) ? -total : total;
    v12[7]  = acc7[0] + acc7[1];
    v12[8]  = acc8[0] + acc8[1];
    v12[9]  = acc9[0] + acc9[1];
    v12[10] = acc10[0] + acc10[1];
    v12[11] = accT[0] - accT[1];

    // in-wave butterfly reduce (64 lanes)
#pragma unroll
    for (int w = 0; w < 12; ++w) {
#pragma unroll
        for (int off = 1; off < 64; off <<= 1)
            v12[w] += __shfl_xor(v12[w], off, 64);
    }
    // cross-wave combine via LDS (reuse xbuf; barrier protects last exchange)
    __syncthreads();
    if (lane == 0) {
#pragma unroll
        for (int w = 0; w < 12; ++w)
            xbuff[((simL << 1) | wv) * 12 + w] = v12[w];
    }
    __syncthreads();
    if (ts < 12) {
        float z = xbuff[(simL << 1) * 12 + ts] +
                  xbuff[((simL << 1) | 1) * 12 + ts];
        outp[ibase + (ts / 3) * 40 + (ts % 3)] = z;
    }
}

__global__ void q4_kernel(const float* __restrict__ inp,
                          const float* __restrict__ cs4,
                          float* __restrict__ outp)
{
    int b = blockIdx.x * blockDim.x + threadIdx.x;
    if (b >= 1024) return;
    float cw[4], sw[4];
#pragma unroll
    for (int j = 0; j < 4; ++j) {
        float x = inp[(b * 4 + j) * 40 + 39];
        __sincosf(0.5f * x, &sw[j], &cw[j]);
    }
    float sr[16], si[16];
#pragma unroll
    for (int k = 0; k < 16; ++k) {
        float v = 1.0f;
#pragma unroll
        for (int j = 0; j < 4; ++j)
            v *= ((k >> (3 - j)) & 1) ? sw[j] : cw[j];
        int ph = __popc(k) & 3;
        sr[k] = (ph == 0) ? v : (ph == 2) ? -v : 0.0f;
        si[k] = (ph == 1) ? -v : (ph == 3) ? v : 0.0f;
    }
#pragma unroll
    for (int l = 0; l < 4; ++l) {
        // RX(theta[4l+w]) on qubit w (bit 3-w)
#pragma unroll
        for (int w = 0; w < 4; ++w) {
            float cg = cs4[2 * (4 * l + w)], sg = cs4[2 * (4 * l + w) + 1];
            const int m = 1 << (3 - w);
#pragma unroll
            for (int k = 0; k < 16; ++k) {
                if (k & m) continue;
                int p2 = k | m;
                float r0 = sr[k], i0 = si[k], r1 = sr[p2], i1 = si[p2];
                sr[k]  = cg * r0 + sg * i1;  si[k]  = cg * i0 - sg * r1;
                sr[p2] = cg * r1 + sg * i0;  si[p2] = cg * i1 - sg * r0;
            }
        }
        // CNOT (0,1),(1,2),(2,3),(3,0)
#pragma unroll
        for (int e = 0; e < 4; ++e) {
            const int cq = e, tq = (e + 1) & 3;
            const int pcb = 1 << (3 - cq), ptb = 1 << (3 - tq);
#pragma unroll
            for (int k = 0; k < 16; ++k) {
                if (!(k & pcb)) continue;
                if (k & ptb) continue;
                int p2 = k | ptb;
                float tr = sr[k], ti = si[k];
                sr[k] = sr[p2]; si[k] = si[p2];
                sr[p2] = tr;    si[p2] = ti;
            }
        }
    }
    float p[16];
#pragma unroll
    for (int k = 0; k < 16; ++k) p[k] = sr[k] * sr[k] + si[k] * si[k];
#pragma unroll
    for (int j = 0; j < 4; ++j) {
        float z = 0.0f;
#pragma unroll
        for (int k = 0; k < 16; ++k)
            z += ((k >> (3 - j)) & 1) ? -p[k] : p[k];
        outp[(b * 4 + j) * 40 + 39] = z;
    }
}

__global__ void prep_kernel(const float* __restrict__ q12,
                            const float* __restrict__ q4,
                            float* __restrict__ cs12,
                            float* __restrict__ cs4)
{
    int idx = blockIdx.x * 256 + threadIdx.x;
    if (idx < 26 * 72) {
        // gate angle = 2*pi*p, half-angle = pi*p
        float s, c;
        sincosf(PI_F * q12[idx], &s, &c);
        cs12[2 * idx]     = c;
        cs12[2 * idx + 1] = s;
    }
    if (idx < 16) {
        float s, c;
        sincosf(0.5f * q4[idx], &s, &c);
        cs4[2 * idx]     = c;
        cs4[2 * idx + 1] = s;
    }
}

__global__ void tmlp_kernel(const float* __restrict__ emb,
                            const float* __restrict__ W,
                            const float* __restrict__ bias,
                            float* __restrict__ t)
{
    __shared__ float se[128];
    int b = blockIdx.x, tid = threadIdx.x;
    float e = emb[b * 128 + tid];
    se[tid] = e / (1.0f + __expf(-e));
    __syncthreads();
    if (tid < 80) {
        float acc = bias[tid];
        for (int k = 0; k < 128; ++k) acc += se[k] * W[k * 80 + tid];
        t[b * 80 + tid] = acc;
    }
}

__global__ void gn0_kernel(const float* __restrict__ h, const float* __restrict__ t,
                           const float* __restrict__ sc, const float* __restrict__ bi,
                           float* __restrict__ outp)
{
    __shared__ float v[160];
    __shared__ float mu[10], rstd[10];
    int b = blockIdx.x, tid = threadIdx.x;
    if (tid < 160) v[tid] = h[b * 160 + tid];
    __syncthreads();
    if (tid < 10) {
        float s1 = 0.0f, s2 = 0.0f;
#pragma unroll
        for (int sp = 0; sp < 4; ++sp)
#pragma unroll
            for (int k = 0; k < 4; ++k) {
                float x = v[sp * 40 + tid * 4 + k];
                s1 += x; s2 += x * x;
            }
        float m = s1 * (1.0f / 16.0f);
        float var = s2 * (1.0f / 16.0f) - m * m;
        mu[tid] = m; rstd[tid] = rsqrtf(var + 1e-6f);
    }
    __syncthreads();
    if (tid < 160) {
        int ch = tid % 40;
        int g = ch >> 2;
        float hn = (v[tid] - mu[g]) * rstd[g] * sc[ch] + bi[ch];
        float scale = t[b * 80 + ch], shift = t[b * 80 + 40 + ch];
        float z = hn * (1.0f + scale) + shift;
        outp[b * 160 + tid] = z / (1.0f + __expf(-z));
    }
}

__global__ void gn1_kernel(const float* __restrict__ h, const float* __restrict__ x,
                           const float* __restrict__ sc, const float* __restrict__ bi,
                           float* __restrict__ outp)
{
    __shared__ float v[160];
    __shared__ float mu[10], rstd[10];
    int b = blockIdx.x, tid = threadIdx.x;
    if (tid < 160) v[tid] = h[b * 160 + tid];
    __syncthreads();
    if (tid < 10) {
        float s1 = 0.0f, s2 = 0.0f;
#pragma unroll
        for (int sp = 0; sp < 4; ++sp)
#pragma unroll
            for (int k = 0; k < 4; ++k) {
                float xx = v[sp * 40 + tid * 4 + k];
                s1 += xx; s2 += xx * xx;
            }
        float m = s1 * (1.0f / 16.0f);
        float var = s2 * (1.0f / 16.0f) - m * m;
        mu[tid] = m; rstd[tid] = rsqrtf(var + 1e-6f);
    }
    __syncthreads();
    if (tid < 160) {
        int ch = tid % 40;
        int g = ch >> 2;
        float hn = (v[tid] - mu[g]) * rstd[g] * sc[ch] + bi[ch];
        float sws = hn / (1.0f + __expf(-hn));
        outp[b * 160 + tid] = x[b * 160 + tid] + sws;
    }
}

extern "C" void kernel_launch(void* const* d_in, const int* in_sizes, int n_in,
                              void* d_out, int out_size, void* d_ws, size_t ws_size,
                              hipStream_t stream)
{
    const float* x    = (const float*)d_in[0];
    const float* temb = (const float*)d_in[1];
    const float* q12  = (const float*)d_in[2];
    const float* q4   = (const float*)d_in[3];
    const float* gn0s = (const float*)d_in[4];
    const float* gn0b = (const float*)d_in[5];
    const float* gn1s = (const float*)d_in[6];
    const float* gn1b = (const float*)d_in[7];
    const float* tw   = (const float*)d_in[8];
    const float* tb   = (const float*)d_in[9];
    float* out = (float*)d_out;

    float* ws   = (float*)d_ws;
    float* cs12 = ws;               // 26*72*2   = 3744
    float* cs4  = cs12 + 3744;      // 32
    float* tbuf = cs4 + 32;         // 1024*80   = 81920
    float* A    = tbuf + 81920;     // 1024*160  = 163840 (raw qpass out)
    float* Bf   = A + 163840;       // 1024*160  = 163840 (gn0 out / qpass2 in)

    prep_kernel<<<8, 256, 0, stream>>>(q12, q4, cs12, cs4);
    tmlp_kernel<<<1024, 128, 0, stream>>>(temb, tw, tb, tbuf);

    // pass 1  (6656 blocks x 2 sims x 2 waves = 13312 sims)
    qpass12_kernel<<<6656, 256, 0, stream>>>(x, cs12, A);
    q4_kernel<<<16, 64, 0, stream>>>(x, cs4, A);
    gn0_kernel<<<1024, 160, 0, stream>>>(A, tbuf, gn0s, gn0b, Bf);

    // pass 2
    qpass12_kernel<<<6656, 256, 0, stream>>>(Bf, cs12 + 13 * 144, A);
    q4_kernel<<<16, 64, 0, stream>>>(Bf, cs4, A);
    gn1_kernel<<<1024, 160, 0, stream>>>(A, x, gn1s, gn1b, out);
}